// Round 1
// baseline (755.259 us; speedup 1.0000x reference)
//
#include <hip/hip_runtime.h>
#include <math.h>

#define CB 2
#define CT 2048
#define CD 1024
#define CH 16
#define CHD 64
#define CWINDOW 512

// ---------------- fp32 tiled GEMM body: C[M,N] = A[M,K] @ W[K,N] ----------------
// M=4096, K=N=1024. BM=BN=128, BK=16, 256 threads, 8x8 micro-tile split in quadrants.
// MODE 0: C row-major [M,N].  MODE 1: C scattered to [B,H,T,HD] per-head layout.
template <int MODE>
__device__ __forceinline__ void gemm_body(const float* __restrict__ A,
                                          const float* __restrict__ W,
                                          float* __restrict__ C) {
  constexpr int K = CD, N = CD;
  __shared__ float As[16][132];
  __shared__ float Bs[16][132];
  const int tid = threadIdx.x;
  const int tx = tid & 15, ty = tid >> 4;
  const int m0 = blockIdx.x * 128, n0 = blockIdx.y * 128;

  float c[8][8];
#pragma unroll
  for (int i = 0; i < 8; ++i)
#pragma unroll
    for (int j = 0; j < 8; ++j) c[i][j] = 0.f;

  for (int k0 = 0; k0 < K; k0 += 16) {
    __syncthreads();
#pragma unroll
    for (int it = 0; it < 2; ++it) {
      int idx = tid + it * 256;
      // A tile: 128 rows x 16 k  (float4 along k), store transposed As[k][m]
      int r = idx >> 2, cc = idx & 3;
      float4 va = *(const float4*)&A[(size_t)(m0 + r) * K + k0 + cc * 4];
      As[cc * 4 + 0][r] = va.x;
      As[cc * 4 + 1][r] = va.y;
      As[cc * 4 + 2][r] = va.z;
      As[cc * 4 + 3][r] = va.w;
      // B tile: 16 k x 128 cols (float4 along n)
      int kr = idx >> 5, c4 = idx & 31;
      float4 vb = *(const float4*)&W[(size_t)(k0 + kr) * N + n0 + c4 * 4];
      *(float4*)&Bs[kr][c4 * 4] = vb;
    }
    __syncthreads();
#pragma unroll
    for (int kk = 0; kk < 16; ++kk) {
      float a[8], bb[8];
      *(float4*)&a[0] = *(const float4*)&As[kk][ty * 4];
      *(float4*)&a[4] = *(const float4*)&As[kk][ty * 4 + 64];
      *(float4*)&bb[0] = *(const float4*)&Bs[kk][tx * 4];
      *(float4*)&bb[4] = *(const float4*)&Bs[kk][tx * 4 + 64];
#pragma unroll
      for (int i = 0; i < 8; ++i)
#pragma unroll
        for (int j = 0; j < 8; ++j) c[i][j] = fmaf(a[i], bb[j], c[i][j]);
    }
  }

#pragma unroll
  for (int i = 0; i < 8; ++i) {
    int m = m0 + ((i < 4) ? (ty * 4 + i) : (64 + ty * 4 + (i - 4)));
#pragma unroll
    for (int jh = 0; jh < 2; ++jh) {
      int cn = n0 + jh * 64 + tx * 4;
      float4 v;
      v.x = c[i][jh * 4 + 0];
      v.y = c[i][jh * 4 + 1];
      v.z = c[i][jh * 4 + 2];
      v.w = c[i][jh * 4 + 3];
      if (MODE == 0) {
        *(float4*)&C[(size_t)m * N + cn] = v;
      } else {
        int b = m >> 11, t = m & (CT - 1);
        int h = cn >> 6, d = cn & 63;
        *(float4*)&C[(((size_t)b * CH + h) * CT + t) * CHD + d] = v;
      }
    }
  }
}

__global__ __launch_bounds__(256, 2) void gemm_qkv(const float* __restrict__ x,
                                                   const float* __restrict__ Wq,
                                                   const float* __restrict__ Wk,
                                                   const float* __restrict__ Wv,
                                                   float* __restrict__ Qh,
                                                   float* __restrict__ Kh,
                                                   float* __restrict__ Vh) {
  const float* W = (blockIdx.z == 0) ? Wq : ((blockIdx.z == 1) ? Wk : Wv);
  float* Cc = (blockIdx.z == 0) ? Qh : ((blockIdx.z == 1) ? Kh : Vh);
  gemm_body<1>(x, W, Cc);
}

__global__ __launch_bounds__(256, 2) void gemm_out(const float* __restrict__ A,
                                                   const float* __restrict__ W,
                                                   float* __restrict__ C) {
  gemm_body<0>(A, W, C);
}

// ---------------- RMSNorm + RoPE, in place on [B,H,T,HD] ----------------
// One wave (64 lanes) per head-row. wid < B*H*T -> Q row, else K row.
__global__ void rmsrope(float* __restrict__ Qh, float* __restrict__ Kh,
                        const float* __restrict__ q_scale,
                        const float* __restrict__ k_scale) {
  const int wid = (int)((blockIdx.x * (size_t)blockDim.x + threadIdx.x) >> 6);
  const int lane = threadIdx.x & 63;
  const int total = CB * CH * CT;
  float* buf;
  const float* scale;
  int row;
  if (wid < total) {
    buf = Qh;
    scale = q_scale;
    row = wid;
  } else {
    buf = Kh;
    scale = k_scale;
    row = wid - total;
  }
  const int t = row & (CT - 1);
  float v = buf[(size_t)row * CHD + lane];
  float ss = v * v;
#pragma unroll
  for (int off = 32; off > 0; off >>= 1) ss += __shfl_xor(ss, off);
  const float rs = rsqrtf(ss * (1.0f / 64.0f) + 1e-6f);
  v = v * rs * scale[lane];
  // rope: freq index = lane % 32; partner lane = lane ^ 32
  const int f = lane & 31;
  const float inv = powf(10000.0f, -(float)f * (1.0f / 32.0f));
  const float ang = (float)t * inv;
  float s, cg;
  sincosf(ang, &s, &cg);
  const float partner = __shfl_xor(v, 32);
  const float rot = (lane < 32) ? -partner : partner;
  buf[(size_t)row * CHD + lane] = v * cg + rot * s;
}

// ---------------- windowed causal attention with sink ----------------
// grid (T/64, B*H), 256 threads. Flash-style over 64-key blocks.
// thread tid: query row qi = tid>>2, group sg = tid&3.
//   scores: owns keys s = si*4+sg (si 0..15);  PV/out: owns dims sg*16..+15.
__global__ __launch_bounds__(256, 2) void attn(const float* __restrict__ Qh,
                                               const float* __restrict__ Kh,
                                               const float* __restrict__ Vh,
                                               const float* __restrict__ sink_logit,
                                               float* __restrict__ AO) {
  __shared__ float Qs[64][68];
  __shared__ float Ks[64][68];
  __shared__ float Vs[64][68];
  __shared__ float Ps[64][68];
  __shared__ float redm[64][4];
  __shared__ float reds[64][4];

  const int tid = threadIdx.x;
  const int qb = blockIdx.x, bh = blockIdx.y;
  const int b = bh >> 4, h = bh & 15;
  const size_t base = (size_t)bh * CT * CHD;
  const float* Qb = Qh + base;
  const float* Kb = Kh + base;
  const float* Vb = Vh + base;
  const int q0 = qb * 64;

  // load Q tile with the 1/sqrt(HD) scale folded in
#pragma unroll
  for (int it = 0; it < 4; ++it) {
    int idx = tid + it * 256;
    int r = idx >> 4, c4 = idx & 15;
    float4 v = *(const float4*)&Qb[(size_t)(q0 + r) * CHD + c4 * 4];
    v.x *= 0.125f;
    v.y *= 0.125f;
    v.z *= 0.125f;
    v.w *= 0.125f;
    *(float4*)&Qs[r][c4 * 4] = v;
  }

  const int qi = tid >> 2, sg = tid & 3;
  const int tq = q0 + qi;
  const int dbase = sg * 16;
  float m_run = sink_logit[h];  // sink acts as initial max...
  float l_run = 1.0f;           // ...with weight exp(sink - m) = 1
  float acc[16];
#pragma unroll
  for (int j = 0; j < 16; ++j) acc[j] = 0.f;

  const int kb_lo = (qb >= 8) ? (qb - 8) : 0;
  for (int kb = kb_lo; kb <= qb; ++kb) {
    __syncthreads();
#pragma unroll
    for (int it = 0; it < 4; ++it) {
      int idx = tid + it * 256;
      int r = idx >> 4, c4 = idx & 15;
      size_t g = (size_t)(kb * 64 + r) * CHD + c4 * 4;
      *(float4*)&Ks[r][c4 * 4] = *(const float4*)&Kb[g];
      *(float4*)&Vs[r][c4 * 4] = *(const float4*)&Vb[g];
    }
    __syncthreads();

    float sc[16];
#pragma unroll
    for (int si = 0; si < 16; ++si) sc[si] = 0.f;
#pragma unroll
    for (int d4 = 0; d4 < 16; ++d4) {
      float4 q = *(const float4*)&Qs[qi][d4 * 4];
#pragma unroll
      for (int si = 0; si < 16; ++si) {
        float4 k = *(const float4*)&Ks[si * 4 + sg][d4 * 4];
        sc[si] += q.x * k.x + q.y * k.y + q.z * k.z + q.w * k.w;
      }
    }

    float pmax = -INFINITY;
#pragma unroll
    for (int si = 0; si < 16; ++si) {
      int ks = kb * 64 + si * 4 + sg;
      if (ks > tq || ks <= tq - CWINDOW) sc[si] = -INFINITY;
      pmax = fmaxf(pmax, sc[si]);
    }
    redm[qi][sg] = pmax;
    __syncthreads();
    float4 rm = *(const float4*)&redm[qi][0];
    float m_new = fmaxf(m_run, fmaxf(fmaxf(rm.x, rm.y), fmaxf(rm.z, rm.w)));
    float alpha = __expf(m_run - m_new);
    m_run = m_new;
    float psum = 0.f;
#pragma unroll
    for (int si = 0; si < 16; ++si) {
      float p = __expf(sc[si] - m_new);  // masked -> exp(-inf)=0
      Ps[qi][si * 4 + sg] = p;
      psum += p;
    }
    reds[qi][sg] = psum;
    __syncthreads();
    float4 rs = *(const float4*)&reds[qi][0];
    l_run = l_run * alpha + (rs.x + rs.y + rs.z + rs.w);
#pragma unroll
    for (int j = 0; j < 16; ++j) acc[j] *= alpha;
    for (int s = 0; s < 64; ++s) {
      float p = Ps[qi][s];
#pragma unroll
      for (int j4 = 0; j4 < 4; ++j4) {
        float4 v = *(const float4*)&Vs[s][dbase + j4 * 4];
        acc[j4 * 4 + 0] = fmaf(p, v.x, acc[j4 * 4 + 0]);
        acc[j4 * 4 + 1] = fmaf(p, v.y, acc[j4 * 4 + 1]);
        acc[j4 * 4 + 2] = fmaf(p, v.z, acc[j4 * 4 + 2]);
        acc[j4 * 4 + 3] = fmaf(p, v.w, acc[j4 * 4 + 3]);
      }
    }
  }

  const float inv_l = 1.0f / l_run;
  const size_t o = ((size_t)(b * CT + tq)) * CD + h * CHD + dbase;
#pragma unroll
  for (int j4 = 0; j4 < 4; ++j4) {
    float4 v;
    v.x = acc[j4 * 4 + 0] * inv_l;
    v.y = acc[j4 * 4 + 1] * inv_l;
    v.z = acc[j4 * 4 + 2] * inv_l;
    v.w = acc[j4 * 4 + 3] * inv_l;
    *(float4*)&AO[o + j4 * 4] = v;
  }
}

extern "C" void kernel_launch(void* const* d_in, const int* in_sizes, int n_in,
                              void* d_out, int out_size, void* d_ws, size_t ws_size,
                              hipStream_t stream) {
  (void)in_sizes;
  (void)n_in;
  (void)out_size;
  (void)ws_size;
  const float* x = (const float*)d_in[0];
  const float* Wq = (const float*)d_in[1];
  const float* Wk = (const float*)d_in[2];
  const float* Wv = (const float*)d_in[3];
  const float* Wo = (const float*)d_in[4];
  const float* q_scale = (const float*)d_in[5];
  const float* k_scale = (const float*)d_in[6];
  const float* sink = (const float*)d_in[7];
  float* out = (float*)d_out;

  const size_t per = (size_t)CB * CH * CT * CHD;  // 4M floats
  float* Qh = (float*)d_ws;
  float* Kh = Qh + per;
  float* Vh = Kh + per;
  float* AO = Vh + per;  // [B*T, D] row-major

  dim3 blk(256);
  gemm_qkv<<<dim3(32, 8, 3), blk, 0, stream>>>(x, Wq, Wk, Wv, Qh, Kh, Vh);
  rmsrope<<<dim3(2 * CB * CH * CT / 4), blk, 0, stream>>>(Qh, Kh, q_scale, k_scale);
  attn<<<dim3(CT / 64, CB * CH), blk, 0, stream>>>(Qh, Kh, Vh, sink, AO);
  gemm_out<<<dim3(32, 8, 1), blk, 0, stream>>>(AO, Wo, out);
}

// Round 2
// 400.913 us; speedup vs baseline: 1.8838x; 1.8838x over previous
//
#include <hip/hip_runtime.h>
#include <math.h>

#define CB 2
#define CT 2048
#define CD 1024
#define CH 16
#define CHD 64
#define CWINDOW 512

typedef __bf16 bf16x8 __attribute__((ext_vector_type(8)));
typedef float floatx4 __attribute__((ext_vector_type(4)));

__device__ __forceinline__ unsigned short f2bf(float f) {
  union { float f; unsigned int u; } v;
  v.f = f;
  unsigned int u = v.u;
  u += 0x7fffu + ((u >> 16) & 1u);  // round-to-nearest-even
  return (unsigned short)(u >> 16);
}
__device__ __forceinline__ float bf2f(unsigned int h) {
  union { unsigned int u; float f; } v;
  v.u = h << 16;
  return v.f;
}

// ---------------- fp32 -> bf16 elementwise convert (x) ----------------
__global__ __launch_bounds__(256) void cvt_x(const float* __restrict__ x,
                                             unsigned short* __restrict__ xb) {
  const int i = blockIdx.x * 256 + threadIdx.x;  // 8 elements per thread
  float4 a = ((const float4*)x)[i * 2];
  float4 b = ((const float4*)x)[i * 2 + 1];
  uint4 o;
  o.x = (unsigned int)f2bf(a.x) | ((unsigned int)f2bf(a.y) << 16);
  o.y = (unsigned int)f2bf(a.z) | ((unsigned int)f2bf(a.w) << 16);
  o.z = (unsigned int)f2bf(b.x) | ((unsigned int)f2bf(b.y) << 16);
  o.w = (unsigned int)f2bf(b.z) | ((unsigned int)f2bf(b.w) << 16);
  ((uint4*)xb)[i] = o;
}

// ---------------- fp32 [K,N] -> bf16 [N,K] transpose+convert (weights) ----------------
__global__ __launch_bounds__(256) void cvt_wt(const float* __restrict__ Wq,
                                              const float* __restrict__ Wk,
                                              const float* __restrict__ Wv,
                                              const float* __restrict__ Wo,
                                              unsigned short* __restrict__ WqT,
                                              unsigned short* __restrict__ WkT,
                                              unsigned short* __restrict__ WvT,
                                              unsigned short* __restrict__ WoT) {
  const float* W = blockIdx.z == 0 ? Wq : blockIdx.z == 1 ? Wk : blockIdx.z == 2 ? Wv : Wo;
  unsigned short* Wt = blockIdx.z == 0 ? WqT : blockIdx.z == 1 ? WkT : blockIdx.z == 2 ? WvT : WoT;
  __shared__ float tile[64][65];
  const int k0 = blockIdx.x * 64, n0 = blockIdx.y * 64;
  const int c = threadIdx.x & 63, r4 = threadIdx.x >> 6;
#pragma unroll
  for (int i = 0; i < 16; ++i) {
    int r = i * 4 + r4;
    tile[r][c] = W[(size_t)(k0 + r) * CD + n0 + c];
  }
  __syncthreads();
#pragma unroll
  for (int i = 0; i < 16; ++i) {
    int r = i * 4 + r4;
    Wt[(size_t)(n0 + r) * CD + k0 + c] = f2bf(tile[c][r]);
  }
}

// ---------------- async 16B global -> LDS ----------------
__device__ __forceinline__ void async16(const unsigned short* g, unsigned short* l) {
  __builtin_amdgcn_global_load_lds(
      (const __attribute__((address_space(1))) unsigned int*)g,
      (__attribute__((address_space(3))) unsigned int*)l, 16, 0, 0);
}

// ---------------- bf16 MFMA GEMM: C[M,N] = A[M,K] @ Bt[N,K]^T ----------------
// 128x128 tile, BK=32, 256 threads = 4 waves, each wave a 64x64 quadrant of
// 4x4 16x16x32 MFMA tiles. A, Bt bf16 row-major (K contiguous).
// MODE 0: C fp32 row-major [M,N].  MODE 1: C bf16 scattered to [B,H,T,HD].
template <int MODE>
__device__ __forceinline__ void mfma_gemm_body(const unsigned short* __restrict__ A,
                                               const unsigned short* __restrict__ Bt,
                                               void* __restrict__ Cout) {
  constexpr int K = CD;
  __shared__ unsigned short As[128 * 32];
  __shared__ unsigned short Bs[128 * 32];
  const int tid = threadIdx.x;
  const int wave = tid >> 6, lane = tid & 63;
  const int m0 = blockIdx.x * 128, n0 = blockIdx.y * 128;
  const int mq = (wave & 1) * 64, nq = (wave >> 1) * 64;

  floatx4 acc[4][4] = {};
  const int srow = lane >> 2;        // staging: row within 16-row group
  const int skc = (lane & 3) * 8;    // staging: k chunk (8 bf16 = 16B)
  const int fr = lane & 15;          // fragment row/col
  const int fk = (lane >> 4) * 8;    // fragment k offset

  for (int k0 = 0; k0 < K; k0 += 32) {
    __syncthreads();
#pragma unroll
    for (int it = 0; it < 2; ++it) {
      const int sub = wave * 2 + it;
      const int row = sub * 16 + srow;
      async16(A + (size_t)(m0 + row) * K + k0 + skc, &As[sub * 512]);
      async16(Bt + (size_t)(n0 + row) * K + k0 + skc, &Bs[sub * 512]);
    }
    __syncthreads();
    bf16x8 af[4], bg[4];
#pragma unroll
    for (int mt = 0; mt < 4; ++mt)
      af[mt] = *(const bf16x8*)&As[(mq + mt * 16 + fr) * 32 + fk];
#pragma unroll
    for (int nt = 0; nt < 4; ++nt)
      bg[nt] = *(const bf16x8*)&Bs[(nq + nt * 16 + fr) * 32 + fk];
#pragma unroll
    for (int mt = 0; mt < 4; ++mt)
#pragma unroll
      for (int nt = 0; nt < 4; ++nt)
        acc[mt][nt] = __builtin_amdgcn_mfma_f32_16x16x32_bf16(af[mt], bg[nt], acc[mt][nt], 0, 0, 0);
  }

  // epilogue: C/D layout col=lane&15, row=(lane>>4)*4+i
#pragma unroll
  for (int mt = 0; mt < 4; ++mt) {
#pragma unroll
    for (int nt = 0; nt < 4; ++nt) {
      const int col = n0 + nq + nt * 16 + (lane & 15);
#pragma unroll
      for (int i = 0; i < 4; ++i) {
        const int m = m0 + mq + mt * 16 + (lane >> 4) * 4 + i;
        if (MODE == 0) {
          ((float*)Cout)[(size_t)m * CD + col] = acc[mt][nt][i];
        } else {
          const int b = m >> 11, t = m & (CT - 1);
          const int h = col >> 6, d = col & 63;
          ((unsigned short*)Cout)[((size_t)(b * CH + h) * CT + t) * CHD + d] = f2bf(acc[mt][nt][i]);
        }
      }
    }
  }
}

__global__ __launch_bounds__(256, 2) void gemm_qkv_mfma(const unsigned short* __restrict__ xb,
                                                        const unsigned short* __restrict__ WqT,
                                                        const unsigned short* __restrict__ WkT,
                                                        const unsigned short* __restrict__ WvT,
                                                        unsigned short* __restrict__ Qh,
                                                        unsigned short* __restrict__ Kh,
                                                        unsigned short* __restrict__ Vh) {
  const unsigned short* Bt = blockIdx.z == 0 ? WqT : blockIdx.z == 1 ? WkT : WvT;
  unsigned short* C = blockIdx.z == 0 ? Qh : blockIdx.z == 1 ? Kh : Vh;
  mfma_gemm_body<1>(xb, Bt, C);
}

__global__ __launch_bounds__(256, 2) void gemm_out_mfma(const unsigned short* __restrict__ AO,
                                                        const unsigned short* __restrict__ WoT,
                                                        float* __restrict__ out) {
  mfma_gemm_body<0>(AO, WoT, out);
}

// ---------------- RMSNorm + RoPE, in place on bf16 [B,H,T,HD] ----------------
__global__ void rmsrope(unsigned short* __restrict__ Qh, unsigned short* __restrict__ Kh,
                        const float* __restrict__ q_scale,
                        const float* __restrict__ k_scale) {
  const int wid = (int)((blockIdx.x * (size_t)blockDim.x + threadIdx.x) >> 6);
  const int lane = threadIdx.x & 63;
  const int total = CB * CH * CT;
  unsigned short* buf;
  const float* scale;
  int row;
  if (wid < total) {
    buf = Qh;
    scale = q_scale;
    row = wid;
  } else {
    buf = Kh;
    scale = k_scale;
    row = wid - total;
  }
  const int t = row & (CT - 1);
  float v = bf2f(buf[(size_t)row * CHD + lane]);
  float ss = v * v;
#pragma unroll
  for (int off = 32; off > 0; off >>= 1) ss += __shfl_xor(ss, off);
  const float rs = rsqrtf(ss * (1.0f / 64.0f) + 1e-6f);
  v = v * rs * scale[lane];
  const int f = lane & 31;
  const float inv = powf(10000.0f, -(float)f * (1.0f / 32.0f));
  const float ang = (float)t * inv;
  float s, cg;
  sincosf(ang, &s, &cg);
  const float partner = __shfl_xor(v, 32);
  const float rot = (lane < 32) ? -partner : partner;
  buf[(size_t)row * CHD + lane] = f2bf(v * cg + rot * s);
}

// ---------------- windowed causal attention with sink (bf16 in/out) ----------------
__device__ __forceinline__ void stage8(const unsigned short* __restrict__ g,
                                       float* __restrict__ dst, float scale) {
  uint4 u = *(const uint4*)g;
  dst[0] = bf2f(u.x & 0xffffu) * scale;
  dst[1] = bf2f(u.x >> 16) * scale;
  dst[2] = bf2f(u.y & 0xffffu) * scale;
  dst[3] = bf2f(u.y >> 16) * scale;
  dst[4] = bf2f(u.z & 0xffffu) * scale;
  dst[5] = bf2f(u.z >> 16) * scale;
  dst[6] = bf2f(u.w & 0xffffu) * scale;
  dst[7] = bf2f(u.w >> 16) * scale;
}

__global__ __launch_bounds__(256, 2) void attn(const unsigned short* __restrict__ Qh,
                                               const unsigned short* __restrict__ Kh,
                                               const unsigned short* __restrict__ Vh,
                                               const float* __restrict__ sink_logit,
                                               unsigned short* __restrict__ AO) {
  __shared__ float Qs[64][68];
  __shared__ float Ks[64][68];
  __shared__ float Vs[64][68];
  __shared__ float Ps[64][68];
  __shared__ float redm[64][4];
  __shared__ float reds[64][4];

  const int tid = threadIdx.x;
  const int qb = blockIdx.x, bh = blockIdx.y;
  const int b = bh >> 4, h = bh & 15;
  const size_t base = (size_t)bh * CT * CHD;
  const unsigned short* Qb = Qh + base;
  const unsigned short* Kb = Kh + base;
  const unsigned short* Vb = Vh + base;
  const int q0 = qb * 64;

#pragma unroll
  for (int it = 0; it < 2; ++it) {
    int idx = tid + it * 256;
    int r = idx >> 3, c8 = (idx & 7) * 8;
    stage8(&Qb[(size_t)(q0 + r) * CHD + c8], &Qs[r][c8], 0.125f);
  }

  const int qi = tid >> 2, sg = tid & 3;
  const int tq = q0 + qi;
  const int dbase = sg * 16;
  float m_run = sink_logit[h];
  float l_run = 1.0f;
  float acc[16];
#pragma unroll
  for (int j = 0; j < 16; ++j) acc[j] = 0.f;

  const int kb_lo = (qb >= 8) ? (qb - 8) : 0;
  for (int kb = kb_lo; kb <= qb; ++kb) {
    __syncthreads();
#pragma unroll
    for (int it = 0; it < 2; ++it) {
      int idx = tid + it * 256;
      int r = idx >> 3, c8 = (idx & 7) * 8;
      size_t g = (size_t)(kb * 64 + r) * CHD + c8;
      stage8(&Kb[g], &Ks[r][c8], 1.0f);
      stage8(&Vb[g], &Vs[r][c8], 1.0f);
    }
    __syncthreads();

    float sc[16];
#pragma unroll
    for (int si = 0; si < 16; ++si) sc[si] = 0.f;
#pragma unroll
    for (int d4 = 0; d4 < 16; ++d4) {
      float4 q = *(const float4*)&Qs[qi][d4 * 4];
#pragma unroll
      for (int si = 0; si < 16; ++si) {
        float4 k = *(const float4*)&Ks[si * 4 + sg][d4 * 4];
        sc[si] += q.x * k.x + q.y * k.y + q.z * k.z + q.w * k.w;
      }
    }

    float pmax = -INFINITY;
#pragma unroll
    for (int si = 0; si < 16; ++si) {
      int ks = kb * 64 + si * 4 + sg;
      if (ks > tq || ks <= tq - CWINDOW) sc[si] = -INFINITY;
      pmax = fmaxf(pmax, sc[si]);
    }
    redm[qi][sg] = pmax;
    __syncthreads();
    float4 rm = *(const float4*)&redm[qi][0];
    float m_new = fmaxf(m_run, fmaxf(fmaxf(rm.x, rm.y), fmaxf(rm.z, rm.w)));
    float alpha = __expf(m_run - m_new);
    m_run = m_new;
    float psum = 0.f;
#pragma unroll
    for (int si = 0; si < 16; ++si) {
      float p = __expf(sc[si] - m_new);
      Ps[qi][si * 4 + sg] = p;
      psum += p;
    }
    reds[qi][sg] = psum;
    __syncthreads();
    float4 rs = *(const float4*)&reds[qi][0];
    l_run = l_run * alpha + (rs.x + rs.y + rs.z + rs.w);
#pragma unroll
    for (int j = 0; j < 16; ++j) acc[j] *= alpha;
    for (int s = 0; s < 64; ++s) {
      float p = Ps[qi][s];
#pragma unroll
      for (int j4 = 0; j4 < 4; ++j4) {
        float4 v = *(const float4*)&Vs[s][dbase + j4 * 4];
        acc[j4 * 4 + 0] = fmaf(p, v.x, acc[j4 * 4 + 0]);
        acc[j4 * 4 + 1] = fmaf(p, v.y, acc[j4 * 4 + 1]);
        acc[j4 * 4 + 2] = fmaf(p, v.z, acc[j4 * 4 + 2]);
        acc[j4 * 4 + 3] = fmaf(p, v.w, acc[j4 * 4 + 3]);
      }
    }
  }

  const float inv_l = 1.0f / l_run;
  unsigned short* dst = AO + ((size_t)(b * CT + tq)) * CD + h * CHD + dbase;
  uint4 o;
  o.x = (unsigned int)f2bf(acc[0] * inv_l) | ((unsigned int)f2bf(acc[1] * inv_l) << 16);
  o.y = (unsigned int)f2bf(acc[2] * inv_l) | ((unsigned int)f2bf(acc[3] * inv_l) << 16);
  o.z = (unsigned int)f2bf(acc[4] * inv_l) | ((unsigned int)f2bf(acc[5] * inv_l) << 16);
  o.w = (unsigned int)f2bf(acc[6] * inv_l) | ((unsigned int)f2bf(acc[7] * inv_l) << 16);
  ((uint4*)dst)[0] = o;
  o.x = (unsigned int)f2bf(acc[8] * inv_l) | ((unsigned int)f2bf(acc[9] * inv_l) << 16);
  o.y = (unsigned int)f2bf(acc[10] * inv_l) | ((unsigned int)f2bf(acc[11] * inv_l) << 16);
  o.z = (unsigned int)f2bf(acc[12] * inv_l) | ((unsigned int)f2bf(acc[13] * inv_l) << 16);
  o.w = (unsigned int)f2bf(acc[14] * inv_l) | ((unsigned int)f2bf(acc[15] * inv_l) << 16);
  ((uint4*)dst)[1] = o;
}

extern "C" void kernel_launch(void* const* d_in, const int* in_sizes, int n_in,
                              void* d_out, int out_size, void* d_ws, size_t ws_size,
                              hipStream_t stream) {
  (void)in_sizes;
  (void)n_in;
  (void)out_size;
  (void)ws_size;
  const float* x = (const float*)d_in[0];
  const float* Wq = (const float*)d_in[1];
  const float* Wk = (const float*)d_in[2];
  const float* Wv = (const float*)d_in[3];
  const float* Wo = (const float*)d_in[4];
  const float* q_scale = (const float*)d_in[5];
  const float* k_scale = (const float*)d_in[6];
  const float* sink = (const float*)d_in[7];
  float* out = (float*)d_out;

  const size_t per = (size_t)CB * CH * CT * CHD;  // 4M elements
  unsigned short* Qh = (unsigned short*)d_ws;
  unsigned short* Kh = Qh + per;
  unsigned short* Vh = Kh + per;
  unsigned short* AO = Vh + per;      // [B*T, D] row-major bf16
  unsigned short* xb = AO + per;      // [B*T, D] bf16
  unsigned short* WqT = xb + per;     // [N,K] bf16 each
  unsigned short* WkT = WqT + (size_t)CD * CD;
  unsigned short* WvT = WkT + (size_t)CD * CD;
  unsigned short* WoT = WvT + (size_t)CD * CD;

  dim3 blk(256);
  cvt_x<<<dim3((CB * CT * CD) / (256 * 8)), blk, 0, stream>>>(x, xb);
  cvt_wt<<<dim3(16, 16, 4), blk, 0, stream>>>(Wq, Wk, Wv, Wo, WqT, WkT, WvT, WoT);
  gemm_qkv_mfma<<<dim3(32, 8, 3), blk, 0, stream>>>(xb, WqT, WkT, WvT, Qh, Kh, Vh);
  rmsrope<<<dim3(2 * CB * CH * CT / 4), blk, 0, stream>>>(Qh, Kh, q_scale, k_scale);
  attn<<<dim3(CT / 64, CB * CH), blk, 0, stream>>>(Qh, Kh, Vh, sink, AO);
  gemm_out_mfma<<<dim3(32, 8), blk, 0, stream>>>(AO, WoT, out);
}

// Round 3
// 226.377 us; speedup vs baseline: 3.3363x; 1.7710x over previous
//
#include <hip/hip_runtime.h>
#include <math.h>

#define CB 2
#define CT 2048
#define CD 1024
#define CH 16
#define CHD 64
#define CWINDOW 512

typedef __bf16 bf16x8 __attribute__((ext_vector_type(8)));
typedef float floatx4 __attribute__((ext_vector_type(4)));

__device__ __forceinline__ unsigned short f2bf(float f) {
  union { float f; unsigned int u; } v;
  v.f = f;
  unsigned int u = v.u;
  u += 0x7fffu + ((u >> 16) & 1u);  // round-to-nearest-even
  return (unsigned short)(u >> 16);
}
__device__ __forceinline__ float bf2f(unsigned int h) {
  union { unsigned int u; float f; } v;
  v.u = h << 16;
  return v.f;
}

// ---------------- fp32 -> bf16 elementwise convert (x) ----------------
__global__ __launch_bounds__(256) void cvt_x(const float* __restrict__ x,
                                             unsigned short* __restrict__ xb) {
  const int i = blockIdx.x * 256 + threadIdx.x;  // 8 elements per thread
  float4 a = ((const float4*)x)[i * 2];
  float4 b = ((const float4*)x)[i * 2 + 1];
  uint4 o;
  o.x = (unsigned int)f2bf(a.x) | ((unsigned int)f2bf(a.y) << 16);
  o.y = (unsigned int)f2bf(a.z) | ((unsigned int)f2bf(a.w) << 16);
  o.z = (unsigned int)f2bf(b.x) | ((unsigned int)f2bf(b.y) << 16);
  o.w = (unsigned int)f2bf(b.z) | ((unsigned int)f2bf(b.w) << 16);
  ((uint4*)xb)[i] = o;
}

// ---------------- fp32 [K,N] -> bf16 [N,K] transpose+convert (weights) ----------------
__global__ __launch_bounds__(256) void cvt_wt(const float* __restrict__ Wq,
                                              const float* __restrict__ Wk,
                                              const float* __restrict__ Wv,
                                              const float* __restrict__ Wo,
                                              unsigned short* __restrict__ WqT,
                                              unsigned short* __restrict__ WkT,
                                              unsigned short* __restrict__ WvT,
                                              unsigned short* __restrict__ WoT) {
  const float* W = blockIdx.z == 0 ? Wq : blockIdx.z == 1 ? Wk : blockIdx.z == 2 ? Wv : Wo;
  unsigned short* Wt = blockIdx.z == 0 ? WqT : blockIdx.z == 1 ? WkT : blockIdx.z == 2 ? WvT : WoT;
  __shared__ float tile[64][65];
  const int k0 = blockIdx.x * 64, n0 = blockIdx.y * 64;
  const int c = threadIdx.x & 63, r4 = threadIdx.x >> 6;
#pragma unroll
  for (int i = 0; i < 16; ++i) {
    int r = i * 4 + r4;
    tile[r][c] = W[(size_t)(k0 + r) * CD + n0 + c];
  }
  __syncthreads();
#pragma unroll
  for (int i = 0; i < 16; ++i) {
    int r = i * 4 + r4;
    Wt[(size_t)(n0 + r) * CD + k0 + c] = f2bf(tile[c][r]);
  }
}

// ---------------- async 16B global -> LDS ----------------
__device__ __forceinline__ void async16(const unsigned short* g, unsigned short* l) {
  __builtin_amdgcn_global_load_lds(
      (const __attribute__((address_space(1))) unsigned int*)g,
      (__attribute__((address_space(3))) unsigned int*)l, 16, 0, 0);
}

// ---------------- bf16 MFMA GEMM: C[M,N] = A[M,K] @ Bt[N,K]^T ----------------
// 128x128 tile, BK=32, 256 threads = 4 waves, each wave a 64x64 quadrant of
// 4x4 16x16x32 MFMA tiles.
// MODE 0: C fp32 row-major [M,N].
// MODE 1: C bf16 scattered to [B,H,T,HD].
// MODE 2: C bf16 scattered to [B,H,HD,T] (transposed V), packed 8B stores.
template <int MODE>
__device__ __forceinline__ void mfma_gemm_body(const unsigned short* __restrict__ A,
                                               const unsigned short* __restrict__ Bt,
                                               void* __restrict__ Cout) {
  constexpr int K = CD;
  __shared__ unsigned short As[128 * 32];
  __shared__ unsigned short Bs[128 * 32];
  const int tid = threadIdx.x;
  const int wave = tid >> 6, lane = tid & 63;
  const int m0 = blockIdx.x * 128, n0 = blockIdx.y * 128;
  const int mq = (wave & 1) * 64, nq = (wave >> 1) * 64;

  floatx4 acc[4][4] = {};
  const int srow = lane >> 2;        // staging: row within 16-row group
  const int skc = (lane & 3) * 8;    // staging: k chunk (8 bf16 = 16B)
  const int fr = lane & 15;          // fragment row/col
  const int fk = (lane >> 4) * 8;    // fragment k offset

  for (int k0 = 0; k0 < K; k0 += 32) {
    __syncthreads();
#pragma unroll
    for (int it = 0; it < 2; ++it) {
      const int sub = wave * 2 + it;
      const int row = sub * 16 + srow;
      async16(A + (size_t)(m0 + row) * K + k0 + skc, &As[sub * 512]);
      async16(Bt + (size_t)(n0 + row) * K + k0 + skc, &Bs[sub * 512]);
    }
    __syncthreads();
    bf16x8 af[4], bg[4];
#pragma unroll
    for (int mt = 0; mt < 4; ++mt)
      af[mt] = *(const bf16x8*)&As[(mq + mt * 16 + fr) * 32 + fk];
#pragma unroll
    for (int nt = 0; nt < 4; ++nt)
      bg[nt] = *(const bf16x8*)&Bs[(nq + nt * 16 + fr) * 32 + fk];
#pragma unroll
    for (int mt = 0; mt < 4; ++mt)
#pragma unroll
      for (int nt = 0; nt < 4; ++nt)
        acc[mt][nt] = __builtin_amdgcn_mfma_f32_16x16x32_bf16(af[mt], bg[nt], acc[mt][nt], 0, 0, 0);
  }

  // epilogue: C/D layout col=lane&15, row=(lane>>4)*4+i
#pragma unroll
  for (int mt = 0; mt < 4; ++mt) {
#pragma unroll
    for (int nt = 0; nt < 4; ++nt) {
      const int col = n0 + nq + nt * 16 + (lane & 15);
      if (MODE == 2) {
        const int mb = m0 + mq + mt * 16 + (lane >> 4) * 4;
        const int b = mb >> 11, t = mb & (CT - 1);
        const int h = col >> 6, d = col & 63;
        ushort4 o;
        o.x = f2bf(acc[mt][nt][0]);
        o.y = f2bf(acc[mt][nt][1]);
        o.z = f2bf(acc[mt][nt][2]);
        o.w = f2bf(acc[mt][nt][3]);
        *(ushort4*)&((unsigned short*)Cout)[((size_t)(b * CH + h) * CHD + d) * CT + t] = o;
      } else {
#pragma unroll
        for (int i = 0; i < 4; ++i) {
          const int m = m0 + mq + mt * 16 + (lane >> 4) * 4 + i;
          if (MODE == 0) {
            ((float*)Cout)[(size_t)m * CD + col] = acc[mt][nt][i];
          } else {
            const int b = m >> 11, t = m & (CT - 1);
            const int h = col >> 6, d = col & 63;
            ((unsigned short*)Cout)[((size_t)(b * CH + h) * CT + t) * CHD + d] = f2bf(acc[mt][nt][i]);
          }
        }
      }
    }
  }
}

__global__ __launch_bounds__(256, 2) void gemm_qk_mfma(const unsigned short* __restrict__ xb,
                                                       const unsigned short* __restrict__ WqT,
                                                       const unsigned short* __restrict__ WkT,
                                                       unsigned short* __restrict__ Qh,
                                                       unsigned short* __restrict__ Kh) {
  const unsigned short* Bt = blockIdx.z == 0 ? WqT : WkT;
  unsigned short* C = blockIdx.z == 0 ? Qh : Kh;
  mfma_gemm_body<1>(xb, Bt, C);
}

__global__ __launch_bounds__(256, 2) void gemm_v_mfma(const unsigned short* __restrict__ xb,
                                                      const unsigned short* __restrict__ WvT,
                                                      unsigned short* __restrict__ Vt) {
  mfma_gemm_body<2>(xb, WvT, Vt);
}

__global__ __launch_bounds__(256, 2) void gemm_out_mfma(const unsigned short* __restrict__ AO,
                                                        const unsigned short* __restrict__ WoT,
                                                        float* __restrict__ out) {
  mfma_gemm_body<0>(AO, WoT, out);
}

// ---------------- RMSNorm + RoPE, in place on bf16 [B,H,T,HD] ----------------
// Q additionally scaled by 1/sqrt(HD) = 0.125 (folded attention scale).
__global__ void rmsrope(unsigned short* __restrict__ Qh, unsigned short* __restrict__ Kh,
                        const float* __restrict__ q_scale,
                        const float* __restrict__ k_scale) {
  const int wid = (int)((blockIdx.x * (size_t)blockDim.x + threadIdx.x) >> 6);
  const int lane = threadIdx.x & 63;
  const int total = CB * CH * CT;
  unsigned short* buf;
  const float* scale;
  int row;
  float oscale;
  if (wid < total) {
    buf = Qh;
    scale = q_scale;
    row = wid;
    oscale = 0.125f;
  } else {
    buf = Kh;
    scale = k_scale;
    row = wid - total;
    oscale = 1.0f;
  }
  const int t = row & (CT - 1);
  float v = bf2f(buf[(size_t)row * CHD + lane]);
  float ss = v * v;
#pragma unroll
  for (int off = 32; off > 0; off >>= 1) ss += __shfl_xor(ss, off);
  const float rs = rsqrtf(ss * (1.0f / 64.0f) + 1e-6f);
  v = v * rs * scale[lane];
  const int f = lane & 31;
  const float inv = powf(10000.0f, -(float)f * (1.0f / 32.0f));
  const float ang = (float)t * inv;
  float s, cg;
  sincosf(ang, &s, &cg);
  const float partner = __shfl_xor(v, 32);
  const float rot = (lane < 32) ? -partner : partner;
  buf[(size_t)row * CHD + lane] = f2bf((v * cg + rot * s) * oscale);
}

// ---------------- MFMA windowed attention with sink ----------------
// Grid (T/64, B*H), 128 threads = 2 waves. Wave w owns queries [w*32, w*32+32).
// Per key-block (64 keys):
//   S^T = K·Q^T via MFMA (A=K[m=key][k=d], B=Q[n=q][k=d]) -> D[row=key][col=q]
//   P = exp(S) (fixed shift m=0; |S|<=8 bounded by rmsnorm), packed b64 write
//   to Ps[q][s]; O^T += Vt·P (A=Vt[m=d][k=s], B=P[n=q][k=s]).
// LDS tiles staged via XOR-swizzled global_load_lds; frag reads swizzle-matched.
__device__ __forceinline__ bf16x8 frag64(const unsigned short* base, int row, int ks, int lane) {
  const int phys = (((ks << 2) + (lane >> 4)) ^ (lane & 7)) << 3;
  return *(const bf16x8*)&base[(row << 6) + phys];
}

__global__ __launch_bounds__(128, 2) void attn_mfma(const unsigned short* __restrict__ Qh,
                                                    const unsigned short* __restrict__ Kh,
                                                    const unsigned short* __restrict__ Vt,
                                                    const float* __restrict__ sink_logit,
                                                    unsigned short* __restrict__ AO) {
  __shared__ unsigned short Qs[64 * 64];
  __shared__ unsigned short Ks[64 * 64];
  __shared__ unsigned short Vs[64 * 64];
  __shared__ unsigned short Ps[64 * 72];  // [q][s], stride 72 (144B, 16B-aligned)

  const int tid = threadIdx.x;
  const int w = tid >> 6, lane = tid & 63;
  const int qb = blockIdx.x, bh = blockIdx.y;
  const int b = bh >> 4, h = bh & 15;
  const int q0 = qb * 64;
  const unsigned short* Qb = Qh + (size_t)bh * CT * CHD;
  const unsigned short* Kb = Kh + (size_t)bh * CT * CHD;
  const unsigned short* Vb = Vt + (size_t)bh * CHD * CT;

  const int l7 = lane & 7, l8 = lane >> 3;
  const int sx8 = (l7 ^ l8) * 8;  // xor-swizzled source chunk (element offset)

  // ---- stage Q tile (rows q0..q0+63) ----
#pragma unroll
  for (int s = 0; s < 4; ++s) {
    const int slab = w * 4 + s;
    async16(Qb + (size_t)(q0 + slab * 8 + l8) * CHD + sx8, &Qs[slab * 512]);
  }
  __syncthreads();
  bf16x8 qf[2][2];
#pragma unroll
  for (int nt = 0; nt < 2; ++nt)
#pragma unroll
    for (int ks = 0; ks < 2; ++ks)
      qf[nt][ks] = frag64(Qs, w * 32 + nt * 16 + (lane & 15), ks, lane);

  floatx4 acc[4][2] = {};  // O^T tiles: [mt over d][nt over q]
  float lsum[2] = {0.f, 0.f};

  const int kb_lo = (qb >= 8) ? (qb - 8) : 0;
  for (int kb = kb_lo; kb <= qb; ++kb) {
    __syncthreads();
#pragma unroll
    for (int s = 0; s < 4; ++s) {
      const int slab = w * 4 + s;
      const int row = slab * 8 + l8;
      async16(Kb + (size_t)(kb * 64 + row) * CHD + sx8, &Ks[slab * 512]);
      async16(Vb + (size_t)row * CT + kb * 64 + sx8, &Vs[slab * 512]);
    }
    __syncthreads();

    // ---- S^T = K · Q^T ----
    floatx4 st[4][2] = {};
#pragma unroll
    for (int ks = 0; ks < 2; ++ks) {
      bf16x8 kf[4];
#pragma unroll
      for (int mt = 0; mt < 4; ++mt)
        kf[mt] = frag64(Ks, mt * 16 + (lane & 15), ks, lane);
#pragma unroll
      for (int mt = 0; mt < 4; ++mt)
#pragma unroll
        for (int nt = 0; nt < 2; ++nt)
          st[mt][nt] = __builtin_amdgcn_mfma_f32_16x16x32_bf16(kf[mt], qf[nt][ks], st[mt][nt], 0, 0, 0);
    }

    // ---- P = exp(S) (m=0 shift), pack to LDS [q][s], accumulate row sums ----
    const bool need_c = (kb == qb);
    const bool need_w = (kb == qb - 8);
#pragma unroll
    for (int mt = 0; mt < 4; ++mt) {
#pragma unroll
      for (int nt = 0; nt < 2; ++nt) {
        const int s_base = kb * 64 + mt * 16 + (lane >> 4) * 4;
        const int t_g = q0 + w * 32 + nt * 16 + (lane & 15);
        ushort4 pk;
        float psum = 0.f;
#pragma unroll
        for (int i = 0; i < 4; ++i) {
          float sv = st[mt][nt][i];
          if (need_c || need_w) {
            const int s_g = s_base + i;
            const bool ok = (!need_c || (s_g <= t_g)) && (!need_w || (s_g > t_g - CWINDOW));
            sv = ok ? sv : -INFINITY;
          }
          const float p = __expf(sv);
          const unsigned short pb = f2bf(p);
          ((unsigned short*)&pk)[i] = pb;
          psum += bf2f(pb);
        }
        lsum[nt] += psum;
        const int qrow = w * 32 + nt * 16 + (lane & 15);
        const int scol = mt * 16 + (lane >> 4) * 4;
        *(ushort4*)&Ps[qrow * 72 + scol] = pk;
      }
    }

    // ---- O^T += Vt · P ----
#pragma unroll
    for (int ks = 0; ks < 2; ++ks) {
      bf16x8 vf[4], pf[2];
#pragma unroll
      for (int mt = 0; mt < 4; ++mt)
        vf[mt] = frag64(Vs, mt * 16 + (lane & 15), ks, lane);
#pragma unroll
      for (int nt = 0; nt < 2; ++nt) {
        const int qrow = w * 32 + nt * 16 + (lane & 15);
        pf[nt] = *(const bf16x8*)&Ps[qrow * 72 + ks * 32 + (lane >> 4) * 8];
      }
#pragma unroll
      for (int mt = 0; mt < 4; ++mt)
#pragma unroll
        for (int nt = 0; nt < 2; ++nt)
          acc[mt][nt] = __builtin_amdgcn_mfma_f32_16x16x32_bf16(vf[mt], pf[nt], acc[mt][nt], 0, 0, 0);
    }
  }

  // ---- finalize: denominator (+ sink), normalize, store O (scatter transpose) ----
  const float sinkw = __expf(sink_logit[h]);
  float inv[2];
#pragma unroll
  for (int nt = 0; nt < 2; ++nt) {
    float l = lsum[nt];
    l += __shfl_xor(l, 16);
    l += __shfl_xor(l, 32);
    inv[nt] = 1.0f / (l + sinkw);
  }
#pragma unroll
  for (int mt = 0; mt < 4; ++mt) {
#pragma unroll
    for (int nt = 0; nt < 2; ++nt) {
      const int t_g = q0 + w * 32 + nt * 16 + (lane & 15);
      const int d0 = mt * 16 + (lane >> 4) * 4;
      ushort4 o;
      o.x = f2bf(acc[mt][nt][0] * inv[nt]);
      o.y = f2bf(acc[mt][nt][1] * inv[nt]);
      o.z = f2bf(acc[mt][nt][2] * inv[nt]);
      o.w = f2bf(acc[mt][nt][3] * inv[nt]);
      *(ushort4*)&AO[(size_t)(b * CT + t_g) * CD + h * CHD + d0] = o;
    }
  }
}

extern "C" void kernel_launch(void* const* d_in, const int* in_sizes, int n_in,
                              void* d_out, int out_size, void* d_ws, size_t ws_size,
                              hipStream_t stream) {
  (void)in_sizes;
  (void)n_in;
  (void)out_size;
  (void)ws_size;
  const float* x = (const float*)d_in[0];
  const float* Wq = (const float*)d_in[1];
  const float* Wk = (const float*)d_in[2];
  const float* Wv = (const float*)d_in[3];
  const float* Wo = (const float*)d_in[4];
  const float* q_scale = (const float*)d_in[5];
  const float* k_scale = (const float*)d_in[6];
  const float* sink = (const float*)d_in[7];
  float* out = (float*)d_out;

  const size_t per = (size_t)CB * CH * CT * CHD;  // 4M elements
  unsigned short* Qh = (unsigned short*)d_ws;     // [B,H,T,HD]
  unsigned short* Kh = Qh + per;                  // [B,H,T,HD]
  unsigned short* Vt = Kh + per;                  // [B,H,HD,T]
  unsigned short* AO = Vt + per;                  // [B*T, D]
  unsigned short* xb = AO + per;                  // [B*T, D]
  unsigned short* WqT = xb + per;                 // [N,K] each
  unsigned short* WkT = WqT + (size_t)CD * CD;
  unsigned short* WvT = WkT + (size_t)CD * CD;
  unsigned short* WoT = WvT + (size_t)CD * CD;

  dim3 blk(256);
  cvt_x<<<dim3((CB * CT * CD) / (256 * 8)), blk, 0, stream>>>(x, xb);
  cvt_wt<<<dim3(16, 16, 4), blk, 0, stream>>>(Wq, Wk, Wv, Wo, WqT, WkT, WvT, WoT);
  gemm_qk_mfma<<<dim3(32, 8, 2), blk, 0, stream>>>(xb, WqT, WkT, Qh, Kh);
  gemm_v_mfma<<<dim3(32, 8), blk, 0, stream>>>(xb, WvT, Vt);
  rmsrope<<<dim3(2 * CB * CH * CT / 4), blk, 0, stream>>>(Qh, Kh, q_scale, k_scale);
  attn_mfma<<<dim3(CT / 64, CB * CH), dim3(128), 0, stream>>>(Qh, Kh, Vt, sink, AO);
  gemm_out_mfma<<<dim3(32, 8), blk, 0, stream>>>(AO, WoT, out);
}

// Round 4
// 182.171 us; speedup vs baseline: 4.1459x; 1.2427x over previous
//
#include <hip/hip_runtime.h>
#include <math.h>

#define CB 2
#define CT 2048
#define CD 1024
#define CH 16
#define CHD 64
#define CWINDOW 512

typedef __bf16 bf16x8 __attribute__((ext_vector_type(8)));
typedef float floatx4 __attribute__((ext_vector_type(4)));

__device__ __forceinline__ unsigned short f2bf(float f) {
  union { float f; unsigned int u; } v;
  v.f = f;
  unsigned int u = v.u;
  u += 0x7fffu + ((u >> 16) & 1u);  // round-to-nearest-even
  return (unsigned short)(u >> 16);
}
__device__ __forceinline__ float bf2f(unsigned int h) {
  union { unsigned int u; float f; } v;
  v.u = h << 16;
  return v.f;
}

// ---------------- fp32 -> bf16 elementwise convert (x) ----------------
__global__ __launch_bounds__(256) void cvt_x(const float* __restrict__ x,
                                             unsigned short* __restrict__ xb) {
  const int i = blockIdx.x * 256 + threadIdx.x;  // 8 elements per thread
  float4 a = ((const float4*)x)[i * 2];
  float4 b = ((const float4*)x)[i * 2 + 1];
  uint4 o;
  o.x = (unsigned int)f2bf(a.x) | ((unsigned int)f2bf(a.y) << 16);
  o.y = (unsigned int)f2bf(a.z) | ((unsigned int)f2bf(a.w) << 16);
  o.z = (unsigned int)f2bf(b.x) | ((unsigned int)f2bf(b.y) << 16);
  o.w = (unsigned int)f2bf(b.z) | ((unsigned int)f2bf(b.w) << 16);
  ((uint4*)xb)[i] = o;
}

// ---------------- fp32 [K,N] -> bf16 [N,K] transpose+convert (weights) ----------------
__global__ __launch_bounds__(256) void cvt_wt(const float* __restrict__ Wq,
                                              const float* __restrict__ Wk,
                                              const float* __restrict__ Wv,
                                              const float* __restrict__ Wo,
                                              unsigned short* __restrict__ WqT,
                                              unsigned short* __restrict__ WkT,
                                              unsigned short* __restrict__ WvT,
                                              unsigned short* __restrict__ WoT) {
  const float* W = blockIdx.z == 0 ? Wq : blockIdx.z == 1 ? Wk : blockIdx.z == 2 ? Wv : Wo;
  unsigned short* Wt = blockIdx.z == 0 ? WqT : blockIdx.z == 1 ? WkT : blockIdx.z == 2 ? WvT : WoT;
  __shared__ float tile[64][65];
  const int k0 = blockIdx.x * 64, n0 = blockIdx.y * 64;
  const int c = threadIdx.x & 63, r4 = threadIdx.x >> 6;
#pragma unroll
  for (int i = 0; i < 16; ++i) {
    int r = i * 4 + r4;
    tile[r][c] = W[(size_t)(k0 + r) * CD + n0 + c];
  }
  __syncthreads();
#pragma unroll
  for (int i = 0; i < 16; ++i) {
    int r = i * 4 + r4;
    Wt[(size_t)(n0 + r) * CD + k0 + c] = f2bf(tile[c][r]);
  }
}

// ---------------- async 16B global -> LDS ----------------
__device__ __forceinline__ void async16(const unsigned short* g, unsigned short* l) {
  __builtin_amdgcn_global_load_lds(
      (const __attribute__((address_space(1))) unsigned int*)g,
      (__attribute__((address_space(3))) unsigned int*)l, 16, 0, 0);
}

// ---------------- bf16 MFMA GEMM: C[M,N] = A[M,K] @ Bt[N,K]^T ----------------
// 128x128 tile, BK=32, 256 threads = 4 waves, each wave a 64x64 quadrant of
// 4x4 16x16x32 MFMA tiles.
// MODE 0: C fp32 row-major [M,N].
// MODE 1: C bf16 scattered to [B,H,T,HD].
// MODE 2: C bf16 scattered to [B,H,HD,T] (transposed V), packed 8B stores.
template <int MODE>
__device__ __forceinline__ void mfma_gemm_body(const unsigned short* __restrict__ A,
                                               const unsigned short* __restrict__ Bt,
                                               void* __restrict__ Cout) {
  constexpr int K = CD;
  __shared__ unsigned short As[128 * 32];
  __shared__ unsigned short Bs[128 * 32];
  const int tid = threadIdx.x;
  const int wave = tid >> 6, lane = tid & 63;
  const int m0 = blockIdx.x * 128, n0 = blockIdx.y * 128;
  const int mq = (wave & 1) * 64, nq = (wave >> 1) * 64;

  floatx4 acc[4][4] = {};
  const int srow = lane >> 2;        // staging: row within 16-row group
  const int skc = (lane & 3) * 8;    // staging: k chunk (8 bf16 = 16B)
  const int fr = lane & 15;          // fragment row/col
  const int fk = (lane >> 4) * 8;    // fragment k offset

  for (int k0 = 0; k0 < K; k0 += 32) {
    __syncthreads();
#pragma unroll
    for (int it = 0; it < 2; ++it) {
      const int sub = wave * 2 + it;
      const int row = sub * 16 + srow;
      async16(A + (size_t)(m0 + row) * K + k0 + skc, &As[sub * 512]);
      async16(Bt + (size_t)(n0 + row) * K + k0 + skc, &Bs[sub * 512]);
    }
    __syncthreads();
    bf16x8 af[4], bg[4];
#pragma unroll
    for (int mt = 0; mt < 4; ++mt)
      af[mt] = *(const bf16x8*)&As[(mq + mt * 16 + fr) * 32 + fk];
#pragma unroll
    for (int nt = 0; nt < 4; ++nt)
      bg[nt] = *(const bf16x8*)&Bs[(nq + nt * 16 + fr) * 32 + fk];
#pragma unroll
    for (int mt = 0; mt < 4; ++mt)
#pragma unroll
      for (int nt = 0; nt < 4; ++nt)
        acc[mt][nt] = __builtin_amdgcn_mfma_f32_16x16x32_bf16(af[mt], bg[nt], acc[mt][nt], 0, 0, 0);
  }

  // epilogue: C/D layout col=lane&15, row=(lane>>4)*4+i
#pragma unroll
  for (int mt = 0; mt < 4; ++mt) {
#pragma unroll
    for (int nt = 0; nt < 4; ++nt) {
      const int col = n0 + nq + nt * 16 + (lane & 15);
      if (MODE == 2) {
        const int mb = m0 + mq + mt * 16 + (lane >> 4) * 4;
        const int b = mb >> 11, t = mb & (CT - 1);
        const int h = col >> 6, d = col & 63;
        ushort4 o;
        o.x = f2bf(acc[mt][nt][0]);
        o.y = f2bf(acc[mt][nt][1]);
        o.z = f2bf(acc[mt][nt][2]);
        o.w = f2bf(acc[mt][nt][3]);
        *(ushort4*)&((unsigned short*)Cout)[((size_t)(b * CH + h) * CHD + d) * CT + t] = o;
      } else {
#pragma unroll
        for (int i = 0; i < 4; ++i) {
          const int m = m0 + mq + mt * 16 + (lane >> 4) * 4 + i;
          if (MODE == 0) {
            ((float*)Cout)[(size_t)m * CD + col] = acc[mt][nt][i];
          } else {
            const int b = m >> 11, t = m & (CT - 1);
            const int h = col >> 6, d = col & 63;
            ((unsigned short*)Cout)[((size_t)(b * CH + h) * CT + t) * CHD + d] = f2bf(acc[mt][nt][i]);
          }
        }
      }
    }
  }
}

// z=0: Q (MODE 1), z=1: K (MODE 1), z=2: V transposed (MODE 2)
__global__ __launch_bounds__(256, 2) void gemm_qkv_mfma(const unsigned short* __restrict__ xb,
                                                        const unsigned short* __restrict__ WqT,
                                                        const unsigned short* __restrict__ WkT,
                                                        const unsigned short* __restrict__ WvT,
                                                        unsigned short* __restrict__ Qh,
                                                        unsigned short* __restrict__ Kh,
                                                        unsigned short* __restrict__ Vt) {
  if (blockIdx.z == 2) {
    mfma_gemm_body<2>(xb, WvT, Vt);
  } else {
    const unsigned short* Bt = blockIdx.z == 0 ? WqT : WkT;
    unsigned short* C = blockIdx.z == 0 ? Qh : Kh;
    mfma_gemm_body<1>(xb, Bt, C);
  }
}

__global__ __launch_bounds__(256, 2) void gemm_out_mfma(const unsigned short* __restrict__ AO,
                                                        const unsigned short* __restrict__ WoT,
                                                        float* __restrict__ out) {
  mfma_gemm_body<0>(AO, WoT, out);
}

// ---------------- RMSNorm + RoPE, in place on bf16 [B,H,T,HD] ----------------
// 4 rows per wave: lane = (r<<4)|c, r=row in wave, c=col group (d = 4c..4c+3).
// HW-intrinsic transcendentals (v_exp/v_sin/v_cos), ushort4 loads/stores.
// Q additionally scaled by 1/sqrt(HD) = 0.125 (folded attention scale).
__global__ __launch_bounds__(256) void rmsrope(unsigned short* __restrict__ Qh,
                                               unsigned short* __restrict__ Kh,
                                               const float* __restrict__ q_scale,
                                               const float* __restrict__ k_scale) {
  const int wid = (int)((blockIdx.x * (size_t)blockDim.x + threadIdx.x) >> 6);
  const int lane = threadIdx.x & 63;
  const int r = lane >> 4, c = lane & 15;
  const int total = CB * CH * CT;  // rows per buffer
  int row = wid * 4 + r;
  unsigned short* buf;
  const float* scale;
  float oscale;
  if (row < total) {
    buf = Qh;
    scale = q_scale;
    oscale = 0.125f;
  } else {
    buf = Kh;
    scale = k_scale;
    row -= total;
    oscale = 1.0f;
  }
  const int t = row & (CT - 1);

  ushort4 u = *(const ushort4*)&buf[(size_t)row * CHD + c * 4];
  float v0 = bf2f(u.x), v1 = bf2f(u.y), v2 = bf2f(u.z), v3 = bf2f(u.w);
  float ss = v0 * v0 + v1 * v1 + v2 * v2 + v3 * v3;
#pragma unroll
  for (int off = 8; off > 0; off >>= 1) ss += __shfl_xor(ss, off);
  const float rs = rsqrtf(ss * (1.0f / 64.0f) + 1e-6f);
  const float4 sc4 = ((const float4*)scale)[c];
  v0 *= rs * sc4.x;
  v1 *= rs * sc4.y;
  v2 *= rs * sc4.z;
  v3 *= rs * sc4.w;
  // partners: d ^ 32  <->  c ^ 8, same component
  const float p0 = __shfl_xor(v0, 8);
  const float p1 = __shfl_xor(v1, 8);
  const float p2 = __shfl_xor(v2, 8);
  const float p3 = __shfl_xor(v3, 8);
  const float rsign = (c < 8) ? -1.0f : 1.0f;
  const float tf = (float)t;
  // inv_freq = 10000^(-f/32) = exp(-f * ln(10000)/32), f = (c&7)*4 + i
  const float fb = (float)((c & 7) * 4);
  const float kf = -0.2878231366242557f;  // -ln(10000)/32
  float out0, out1, out2, out3;
  {
    const float ang = tf * __expf((fb + 0.f) * kf);
    out0 = (v0 * __cosf(ang) + rsign * p0 * __sinf(ang)) * oscale;
  }
  {
    const float ang = tf * __expf((fb + 1.f) * kf);
    out1 = (v1 * __cosf(ang) + rsign * p1 * __sinf(ang)) * oscale;
  }
  {
    const float ang = tf * __expf((fb + 2.f) * kf);
    out2 = (v2 * __cosf(ang) + rsign * p2 * __sinf(ang)) * oscale;
  }
  {
    const float ang = tf * __expf((fb + 3.f) * kf);
    out3 = (v3 * __cosf(ang) + rsign * p3 * __sinf(ang)) * oscale;
  }
  ushort4 o;
  o.x = f2bf(out0);
  o.y = f2bf(out1);
  o.z = f2bf(out2);
  o.w = f2bf(out3);
  *(ushort4*)&buf[(size_t)row * CHD + c * 4] = o;
}

// ---------------- MFMA windowed attention with sink ----------------
__device__ __forceinline__ bf16x8 frag64(const unsigned short* base, int row, int ks, int lane) {
  const int phys = (((ks << 2) + (lane >> 4)) ^ (lane & 7)) << 3;
  return *(const bf16x8*)&base[(row << 6) + phys];
}

__global__ __launch_bounds__(128, 2) void attn_mfma(const unsigned short* __restrict__ Qh,
                                                    const unsigned short* __restrict__ Kh,
                                                    const unsigned short* __restrict__ Vt,
                                                    const float* __restrict__ sink_logit,
                                                    unsigned short* __restrict__ AO) {
  __shared__ unsigned short Qs[64 * 64];
  __shared__ unsigned short Ks[64 * 64];
  __shared__ unsigned short Vs[64 * 64];
  __shared__ unsigned short Ps[64 * 72];  // [q][s], stride 72 (144B, 16B-aligned)

  const int tid = threadIdx.x;
  const int w = tid >> 6, lane = tid & 63;
  const int qb = blockIdx.x, bh = blockIdx.y;
  const int b = bh >> 4, h = bh & 15;
  const int q0 = qb * 64;
  const unsigned short* Qb = Qh + (size_t)bh * CT * CHD;
  const unsigned short* Kb = Kh + (size_t)bh * CT * CHD;
  const unsigned short* Vb = Vt + (size_t)bh * CHD * CT;

  const int l7 = lane & 7, l8 = lane >> 3;
  const int sx8 = (l7 ^ l8) * 8;  // xor-swizzled source chunk (element offset)

  // ---- stage Q tile (rows q0..q0+63) ----
#pragma unroll
  for (int s = 0; s < 4; ++s) {
    const int slab = w * 4 + s;
    async16(Qb + (size_t)(q0 + slab * 8 + l8) * CHD + sx8, &Qs[slab * 512]);
  }
  __syncthreads();
  bf16x8 qf[2][2];
#pragma unroll
  for (int nt = 0; nt < 2; ++nt)
#pragma unroll
    for (int ks = 0; ks < 2; ++ks)
      qf[nt][ks] = frag64(Qs, w * 32 + nt * 16 + (lane & 15), ks, lane);

  floatx4 acc[4][2] = {};  // O^T tiles: [mt over d][nt over q]
  float lsum[2] = {0.f, 0.f};

  const int kb_lo = (qb >= 8) ? (qb - 8) : 0;
  for (int kb = kb_lo; kb <= qb; ++kb) {
    __syncthreads();
#pragma unroll
    for (int s = 0; s < 4; ++s) {
      const int slab = w * 4 + s;
      const int row = slab * 8 + l8;
      async16(Kb + (size_t)(kb * 64 + row) * CHD + sx8, &Ks[slab * 512]);
      async16(Vb + (size_t)row * CT + kb * 64 + sx8, &Vs[slab * 512]);
    }
    __syncthreads();

    // ---- S^T = K · Q^T ----
    floatx4 st[4][2] = {};
#pragma unroll
    for (int ks = 0; ks < 2; ++ks) {
      bf16x8 kf[4];
#pragma unroll
      for (int mt = 0; mt < 4; ++mt)
        kf[mt] = frag64(Ks, mt * 16 + (lane & 15), ks, lane);
#pragma unroll
      for (int mt = 0; mt < 4; ++mt)
#pragma unroll
        for (int nt = 0; nt < 2; ++nt)
          st[mt][nt] = __builtin_amdgcn_mfma_f32_16x16x32_bf16(kf[mt], qf[nt][ks], st[mt][nt], 0, 0, 0);
    }

    // ---- P = exp(S) (m=0 shift), pack to LDS [q][s], accumulate row sums ----
    const bool need_c = (kb == qb);
    const bool need_w = (kb == qb - 8);
#pragma unroll
    for (int mt = 0; mt < 4; ++mt) {
#pragma unroll
      for (int nt = 0; nt < 2; ++nt) {
        const int s_base = kb * 64 + mt * 16 + (lane >> 4) * 4;
        const int t_g = q0 + w * 32 + nt * 16 + (lane & 15);
        ushort4 pk;
        float psum = 0.f;
#pragma unroll
        for (int i = 0; i < 4; ++i) {
          float sv = st[mt][nt][i];
          if (need_c || need_w) {
            const int s_g = s_base + i;
            const bool ok = (!need_c || (s_g <= t_g)) && (!need_w || (s_g > t_g - CWINDOW));
            sv = ok ? sv : -INFINITY;
          }
          const float p = __expf(sv);
          const unsigned short pb = f2bf(p);
          ((unsigned short*)&pk)[i] = pb;
          psum += bf2f(pb);
        }
        lsum[nt] += psum;
        const int qrow = w * 32 + nt * 16 + (lane & 15);
        const int scol = mt * 16 + (lane >> 4) * 4;
        *(ushort4*)&Ps[qrow * 72 + scol] = pk;
      }
    }

    // ---- O^T += Vt · P ----
#pragma unroll
    for (int ks = 0; ks < 2; ++ks) {
      bf16x8 vf[4], pf[2];
#pragma unroll
      for (int mt = 0; mt < 4; ++mt)
        vf[mt] = frag64(Vs, mt * 16 + (lane & 15), ks, lane);
#pragma unroll
      for (int nt = 0; nt < 2; ++nt) {
        const int qrow = w * 32 + nt * 16 + (lane & 15);
        pf[nt] = *(const bf16x8*)&Ps[qrow * 72 + ks * 32 + (lane >> 4) * 8];
      }
#pragma unroll
      for (int mt = 0; mt < 4; ++mt)
#pragma unroll
        for (int nt = 0; nt < 2; ++nt)
          acc[mt][nt] = __builtin_amdgcn_mfma_f32_16x16x32_bf16(vf[mt], pf[nt], acc[mt][nt], 0, 0, 0);
    }
  }

  // ---- finalize: denominator (+ sink), normalize, store O (scatter transpose) ----
  const float sinkw = __expf(sink_logit[h]);
  float inv[2];
#pragma unroll
  for (int nt = 0; nt < 2; ++nt) {
    float l = lsum[nt];
    l += __shfl_xor(l, 16);
    l += __shfl_xor(l, 32);
    inv[nt] = 1.0f / (l + sinkw);
  }
#pragma unroll
  for (int mt = 0; mt < 4; ++mt) {
#pragma unroll
    for (int nt = 0; nt < 2; ++nt) {
      const int t_g = q0 + w * 32 + nt * 16 + (lane & 15);
      const int d0 = mt * 16 + (lane >> 4) * 4;
      ushort4 o;
      o.x = f2bf(acc[mt][nt][0] * inv[nt]);
      o.y = f2bf(acc[mt][nt][1] * inv[nt]);
      o.z = f2bf(acc[mt][nt][2] * inv[nt]);
      o.w = f2bf(acc[mt][nt][3] * inv[nt]);
      *(ushort4*)&AO[(size_t)(b * CT + t_g) * CD + h * CHD + d0] = o;
    }
  }
}

extern "C" void kernel_launch(void* const* d_in, const int* in_sizes, int n_in,
                              void* d_out, int out_size, void* d_ws, size_t ws_size,
                              hipStream_t stream) {
  (void)in_sizes;
  (void)n_in;
  (void)out_size;
  (void)ws_size;
  const float* x = (const float*)d_in[0];
  const float* Wq = (const float*)d_in[1];
  const float* Wk = (const float*)d_in[2];
  const float* Wv = (const float*)d_in[3];
  const float* Wo = (const float*)d_in[4];
  const float* q_scale = (const float*)d_in[5];
  const float* k_scale = (const float*)d_in[6];
  const float* sink = (const float*)d_in[7];
  float* out = (float*)d_out;

  const size_t per = (size_t)CB * CH * CT * CHD;  // 4M elements
  unsigned short* Qh = (unsigned short*)d_ws;     // [B,H,T,HD]
  unsigned short* Kh = Qh + per;                  // [B,H,T,HD]
  unsigned short* Vt = Kh + per;                  // [B,H,HD,T]
  unsigned short* AO = Vt + per;                  // [B*T, D]
  unsigned short* xb = AO + per;                  // [B*T, D]
  unsigned short* WqT = xb + per;                 // [N,K] each
  unsigned short* WkT = WqT + (size_t)CD * CD;
  unsigned short* WvT = WkT + (size_t)CD * CD;
  unsigned short* WoT = WvT + (size_t)CD * CD;

  dim3 blk(256);
  cvt_x<<<dim3((CB * CT * CD) / (256 * 8)), blk, 0, stream>>>(x, xb);
  cvt_wt<<<dim3(16, 16, 4), blk, 0, stream>>>(Wq, Wk, Wv, Wo, WqT, WkT, WvT, WoT);
  gemm_qkv_mfma<<<dim3(32, 8, 3), blk, 0, stream>>>(xb, WqT, WkT, WvT, Qh, Kh, Vt);
  rmsrope<<<dim3(2 * CB * CH * CT / 16), blk, 0, stream>>>(Qh, Kh, q_scale, k_scale);
  attn_mfma<<<dim3(CT / 64, CB * CH), dim3(128), 0, stream>>>(Qh, Kh, Vt, sink, AO);
  gemm_out_mfma<<<dim3(32, 8), blk, 0, stream>>>(AO, WoT, out);
}

// Round 6
// 173.250 us; speedup vs baseline: 4.3594x; 1.0515x over previous
//
#include <hip/hip_runtime.h>
#include <math.h>

#define CB 2
#define CT 2048
#define CD 1024
#define CH 16
#define CHD 64
#define CWINDOW 512

typedef __bf16 bf16x8 __attribute__((ext_vector_type(8)));
typedef float floatx4 __attribute__((ext_vector_type(4)));

__device__ __forceinline__ unsigned short f2bf(float f) {
  union { float f; unsigned int u; } v;
  v.f = f;
  unsigned int u = v.u;
  u += 0x7fffu + ((u >> 16) & 1u);  // round-to-nearest-even
  return (unsigned short)(u >> 16);
}
__device__ __forceinline__ float bf2f(unsigned int h) {
  union { unsigned int u; float f; } v;
  v.u = h << 16;
  return v.f;
}

// ---------------- fused convert: weights transpose->bf16 [N,K] + x->bf16 ----------------
// grid (16,16,12): z<4 -> weight tile (Wq,Wk,Wv,Wo); z>=4 -> x chunk.
__global__ __launch_bounds__(256) void cvt_all(const float* __restrict__ x,
                                               const float* __restrict__ Wq,
                                               const float* __restrict__ Wk,
                                               const float* __restrict__ Wv,
                                               const float* __restrict__ Wo,
                                               unsigned short* __restrict__ xb,
                                               unsigned short* __restrict__ WqT,
                                               unsigned short* __restrict__ WkT,
                                               unsigned short* __restrict__ WvT,
                                               unsigned short* __restrict__ WoT) {
  const int z = blockIdx.z;
  if (z < 4) {
    const float* W = z == 0 ? Wq : z == 1 ? Wk : z == 2 ? Wv : Wo;
    unsigned short* Wt = z == 0 ? WqT : z == 1 ? WkT : z == 2 ? WvT : WoT;
    __shared__ float tile[64][65];
    const int k0 = blockIdx.x * 64, n0 = blockIdx.y * 64;
    const int c = threadIdx.x & 63, r4 = threadIdx.x >> 6;
#pragma unroll
    for (int i = 0; i < 16; ++i) {
      int r = i * 4 + r4;
      tile[r][c] = W[(size_t)(k0 + r) * CD + n0 + c];
    }
    __syncthreads();
#pragma unroll
    for (int i = 0; i < 16; ++i) {
      int r = i * 4 + r4;
      Wt[(size_t)(n0 + r) * CD + k0 + c] = f2bf(tile[c][r]);
    }
  } else {
    const int idx = (z - 4) * 256 + blockIdx.y * 16 + blockIdx.x;
    const int i = idx * 256 + threadIdx.x;  // 8 floats per thread
    float4 a = ((const float4*)x)[i * 2];
    float4 b = ((const float4*)x)[i * 2 + 1];
    uint4 o;
    o.x = (unsigned int)f2bf(a.x) | ((unsigned int)f2bf(a.y) << 16);
    o.y = (unsigned int)f2bf(a.z) | ((unsigned int)f2bf(a.w) << 16);
    o.z = (unsigned int)f2bf(b.x) | ((unsigned int)f2bf(b.y) << 16);
    o.w = (unsigned int)f2bf(b.z) | ((unsigned int)f2bf(b.w) << 16);
    ((uint4*)xb)[i] = o;
  }
}

// ---------------- async 16B global -> LDS ----------------
__device__ __forceinline__ void async16(const unsigned short* g, unsigned short* l) {
  __builtin_amdgcn_global_load_lds(
      (const __attribute__((address_space(1))) unsigned int*)g,
      (__attribute__((address_space(3))) unsigned int*)l, 16, 0, 0);
}

// ---------------- bf16 MFMA GEMM: C[M,N] = A[M,K] @ Bt[N,K]^T ----------------
// 128x128 tile, BK=32, 256 threads = 4 waves, each wave a 64x64 quadrant of
// 4x4 16x16x32 MFMA tiles.
// MODE 0: C fp32 row-major [M,N].
// MODE 1: fused rmsnorm+rope epilogue, C bf16 [B,H,T,HD] (Q with oscale=0.125, K with 1).
// MODE 2: C bf16 scattered to [B,H,HD,T] (transposed V), packed 8B stores.
template <int MODE>
__device__ __forceinline__ void mfma_gemm_body(const unsigned short* __restrict__ A,
                                               const unsigned short* __restrict__ Bt,
                                               void* __restrict__ Cout,
                                               const float* __restrict__ scale,
                                               float oscale) {
  constexpr int K = CD;
  __shared__ unsigned short As[128 * 32];
  __shared__ unsigned short Bs[128 * 32];
  const int tid = threadIdx.x;
  const int wave = tid >> 6, lane = tid & 63;
  const int m0 = blockIdx.x * 128, n0 = blockIdx.y * 128;
  const int mq = (wave & 1) * 64, nq = (wave >> 1) * 64;

  floatx4 acc[4][4] = {};
  const int srow = lane >> 2;
  const int skc = (lane & 3) * 8;
  const int fr = lane & 15;
  const int fk = (lane >> 4) * 8;

  for (int k0 = 0; k0 < K; k0 += 32) {
    __syncthreads();
#pragma unroll
    for (int it = 0; it < 2; ++it) {
      const int sub = wave * 2 + it;
      const int row = sub * 16 + srow;
      async16(A + (size_t)(m0 + row) * K + k0 + skc, &As[sub * 512]);
      async16(Bt + (size_t)(n0 + row) * K + k0 + skc, &Bs[sub * 512]);
    }
    __syncthreads();
    bf16x8 af[4], bg[4];
#pragma unroll
    for (int mt = 0; mt < 4; ++mt)
      af[mt] = *(const bf16x8*)&As[(mq + mt * 16 + fr) * 32 + fk];
#pragma unroll
    for (int nt = 0; nt < 4; ++nt)
      bg[nt] = *(const bf16x8*)&Bs[(nq + nt * 16 + fr) * 32 + fk];
#pragma unroll
    for (int mt = 0; mt < 4; ++mt)
#pragma unroll
      for (int nt = 0; nt < 4; ++nt)
        acc[mt][nt] = __builtin_amdgcn_mfma_f32_16x16x32_bf16(af[mt], bg[nt], acc[mt][nt], 0, 0, 0);
  }

  // epilogue: C/D layout col=lane&15, row=(lane>>4)*4+i
  if (MODE == 1) {
    // rows = tokens; cols within quadrant = one head's 64 dims (d = nt*16+c).
    const int c = lane & 15, g = lane >> 4;
    const int hh = (n0 + nq) >> 6;  // head index (wave-uniform)
    const float kf = -0.2878231366242557f;  // -ln(10000)/32
    const float inv0 = __expf((float)c * kf);
    const float inv1 = __expf((float)(16 + c) * kf);
    float sc[4];
#pragma unroll
    for (int nt = 0; nt < 4; ++nt) sc[nt] = scale[nt * 16 + c];
#pragma unroll
    for (int mt = 0; mt < 4; ++mt) {
#pragma unroll
      for (int i = 0; i < 4; ++i) {
        const int m = m0 + mq + mt * 16 + g * 4 + i;
        const int b = m >> 11, t = m & (CT - 1);
        float v0 = acc[mt][0][i], v1 = acc[mt][1][i];
        float v2 = acc[mt][2][i], v3 = acc[mt][3][i];
        float ss = v0 * v0 + v1 * v1 + v2 * v2 + v3 * v3;
#pragma unroll
        for (int off = 8; off > 0; off >>= 1) ss += __shfl_xor(ss, off);
        const float rs = rsqrtf(ss * (1.0f / 64.0f) + 1e-6f);
        v0 *= rs * sc[0];
        v1 *= rs * sc[1];
        v2 *= rs * sc[2];
        v3 *= rs * sc[3];
        const float tf = (float)t;
        const float a0 = tf * inv0, a1 = tf * inv1;
        const float s0 = __sinf(a0), c0 = __cosf(a0);
        const float s1 = __sinf(a1), c1 = __cosf(a1);
        unsigned short* dst = (unsigned short*)Cout + ((size_t)(b * CH + hh) * CT + t) * CHD;
        dst[c] = f2bf((v0 * c0 - v2 * s0) * oscale);
        dst[16 + c] = f2bf((v1 * c1 - v3 * s1) * oscale);
        dst[32 + c] = f2bf((v2 * c0 + v0 * s0) * oscale);
        dst[48 + c] = f2bf((v3 * c1 + v1 * s1) * oscale);
      }
    }
  } else {
#pragma unroll
    for (int mt = 0; mt < 4; ++mt) {
#pragma unroll
      for (int nt = 0; nt < 4; ++nt) {
        const int col = n0 + nq + nt * 16 + (lane & 15);
        if (MODE == 2) {
          const int mb = m0 + mq + mt * 16 + (lane >> 4) * 4;
          const int b = mb >> 11, t = mb & (CT - 1);
          const int h = col >> 6, d = col & 63;
          ushort4 o;
          o.x = f2bf(acc[mt][nt][0]);
          o.y = f2bf(acc[mt][nt][1]);
          o.z = f2bf(acc[mt][nt][2]);
          o.w = f2bf(acc[mt][nt][3]);
          *(ushort4*)&((unsigned short*)Cout)[((size_t)(b * CH + h) * CHD + d) * CT + t] = o;
        } else {
#pragma unroll
          for (int i = 0; i < 4; ++i) {
            const int m = m0 + mq + mt * 16 + (lane >> 4) * 4 + i;
            ((float*)Cout)[(size_t)m * CD + col] = acc[mt][nt][i];
          }
        }
      }
    }
  }
}

// z=0: Q (norm+rope, 0.125), z=1: K (norm+rope), z=2: V transposed
__global__ __launch_bounds__(256, 2) void gemm_qkv_mfma(const unsigned short* __restrict__ xb,
                                                        const unsigned short* __restrict__ WqT,
                                                        const unsigned short* __restrict__ WkT,
                                                        const unsigned short* __restrict__ WvT,
                                                        unsigned short* __restrict__ Qh,
                                                        unsigned short* __restrict__ Kh,
                                                        unsigned short* __restrict__ Vt,
                                                        const float* __restrict__ q_scale,
                                                        const float* __restrict__ k_scale) {
  if (blockIdx.z == 2) {
    mfma_gemm_body<2>(xb, WvT, Vt, nullptr, 1.0f);
  } else if (blockIdx.z == 0) {
    mfma_gemm_body<1>(xb, WqT, Qh, q_scale, 0.125f);
  } else {
    mfma_gemm_body<1>(xb, WkT, Kh, k_scale, 1.0f);
  }
}

__global__ __launch_bounds__(256, 2) void gemm_out_mfma(const unsigned short* __restrict__ AO,
                                                        const unsigned short* __restrict__ WoT,
                                                        float* __restrict__ out) {
  mfma_gemm_body<0>(AO, WoT, out, nullptr, 1.0f);
}

// ---------------- MFMA windowed attention with sink ----------------
// Grid (T/128, B*H), 256 threads = 4 waves; wave w owns queries [q0+w*32, +32).
// Per 64-key block: S^T = K·Q^T (MFMA); P = exp(S) (m=0 shift; |S|<=8 by rmsnorm);
// O^T += Vt·P. Fully-masked tiles skipped per-wave (uniform branch).
__device__ __forceinline__ bf16x8 frag64(const unsigned short* base, int row, int ks, int lane) {
  const int phys = (((ks << 2) + (lane >> 4)) ^ (lane & 7)) << 3;
  return *(const bf16x8*)&base[(row << 6) + phys];
}

__global__ __launch_bounds__(256, 2) void attn_mfma(const unsigned short* __restrict__ Qh,
                                                    const unsigned short* __restrict__ Kh,
                                                    const unsigned short* __restrict__ Vt,
                                                    const float* __restrict__ sink_logit,
                                                    unsigned short* __restrict__ AO) {
  __shared__ unsigned short Qs[128 * 64];
  __shared__ unsigned short Ks[64 * 64];
  __shared__ unsigned short Vs[64 * 64];
  __shared__ unsigned short Ps[128 * 72];  // [q][s], stride 72

  const int tid = threadIdx.x;
  const int w = tid >> 6, lane = tid & 63;
  const int qb = blockIdx.x, bh = blockIdx.y;
  const int b = bh >> 4, h = bh & 15;
  const int q0 = qb * 128;
  const unsigned short* Qb = Qh + (size_t)bh * CT * CHD;
  const unsigned short* Kb = Kh + (size_t)bh * CT * CHD;
  const unsigned short* Vb = Vt + (size_t)bh * CHD * CT;

  const int l7 = lane & 7, l8 = lane >> 3;
  const int sx8 = (l7 ^ l8) * 8;  // xor-swizzled source chunk

  // ---- stage Q tile (128 rows): 16 slabs of 8 rows, 4 per wave ----
#pragma unroll
  for (int s = 0; s < 4; ++s) {
    const int slab = w * 4 + s;
    async16(Qb + (size_t)(q0 + slab * 8 + l8) * CHD + sx8, &Qs[slab * 512]);
  }
  __syncthreads();
  bf16x8 qf[2][2];
#pragma unroll
  for (int nt = 0; nt < 2; ++nt)
#pragma unroll
    for (int ks = 0; ks < 2; ++ks)
      qf[nt][ks] = frag64(Qs, w * 32 + nt * 16 + (lane & 15), ks, lane);

  floatx4 acc[4][2] = {};  // O^T tiles: [mt over d][nt over q]
  float lsum[2] = {0.f, 0.f};
  const int qw = q0 + w * 32;  // wave's first query

  const int kb_lo = (qb >= 4) ? (qb * 2 - 8) : 0;
  const int kb_hi = qb * 2 + 1;
  for (int kb = kb_lo; kb <= kb_hi; ++kb) {
    __syncthreads();
#pragma unroll
    for (int s = 0; s < 2; ++s) {
      const int slab = w * 2 + s;
      const int row = slab * 8 + l8;
      async16(Kb + (size_t)(kb * 64 + row) * CHD + sx8, &Ks[slab * 512]);
      async16(Vb + (size_t)row * CT + kb * 64 + sx8, &Vs[slab * 512]);
    }
    __syncthreads();

    const int kmin = kb * 64, kmax = kb * 64 + 63;
    if (kmin > qw + 31 || kmax <= qw - CWINDOW) continue;  // fully masked for this wave

    // ---- S^T = K · Q^T ----
    floatx4 st[4][2] = {};
#pragma unroll
    for (int ks = 0; ks < 2; ++ks) {
      bf16x8 kf[4];
#pragma unroll
      for (int mt = 0; mt < 4; ++mt)
        kf[mt] = frag64(Ks, mt * 16 + (lane & 15), ks, lane);
#pragma unroll
      for (int mt = 0; mt < 4; ++mt)
#pragma unroll
        for (int nt = 0; nt < 2; ++nt)
          st[mt][nt] = __builtin_amdgcn_mfma_f32_16x16x32_bf16(kf[mt], qf[nt][ks], st[mt][nt], 0, 0, 0);
    }

    // ---- P = exp(S), pack to LDS [q][s], accumulate row sums ----
    const bool need_c = (kmax > qw);
    const bool need_w = (kmin <= qw + 31 - CWINDOW);
#pragma unroll
    for (int mt = 0; mt < 4; ++mt) {
#pragma unroll
      for (int nt = 0; nt < 2; ++nt) {
        const int s_base = kb * 64 + mt * 16 + (lane >> 4) * 4;
        const int t_g = q0 + w * 32 + nt * 16 + (lane & 15);
        ushort4 pk;
        float psum = 0.f;
#pragma unroll
        for (int i = 0; i < 4; ++i) {
          float sv = st[mt][nt][i];
          if (need_c || need_w) {
            const int s_g = s_base + i;
            const bool ok = (!need_c || (s_g <= t_g)) && (!need_w || (s_g > t_g - CWINDOW));
            sv = ok ? sv : -INFINITY;
          }
          const float p = __expf(sv);
          const unsigned short pb = f2bf(p);
          ((unsigned short*)&pk)[i] = pb;
          psum += bf2f(pb);
        }
        lsum[nt] += psum;
        const int qrow = w * 32 + nt * 16 + (lane & 15);
        const int scol = mt * 16 + (lane >> 4) * 4;
        *(ushort4*)&Ps[qrow * 72 + scol] = pk;
      }
    }

    // ---- O^T += Vt · P ----
#pragma unroll
    for (int ks = 0; ks < 2; ++ks) {
      bf16x8 vf[4], pf[2];
#pragma unroll
      for (int mt = 0; mt < 4; ++mt)
        vf[mt] = frag64(Vs, mt * 16 + (lane & 15), ks, lane);
#pragma unroll
      for (int nt = 0; nt < 2; ++nt) {
        const int qrow = w * 32 + nt * 16 + (lane & 15);
        pf[nt] = *(const bf16x8*)&Ps[qrow * 72 + ks * 32 + (lane >> 4) * 8];
      }
#pragma unroll
      for (int mt = 0; mt < 4; ++mt)
#pragma unroll
        for (int nt = 0; nt < 2; ++nt)
          acc[mt][nt] = __builtin_amdgcn_mfma_f32_16x16x32_bf16(vf[mt], pf[nt], acc[mt][nt], 0, 0, 0);
    }
  }

  // ---- finalize: denominator (+ sink), normalize, store O ----
  const float sinkw = __expf(sink_logit[h]);
  float inv[2];
#pragma unroll
  for (int nt = 0; nt < 2; ++nt) {
    float l = lsum[nt];
    l += __shfl_xor(l, 16);
    l += __shfl_xor(l, 32);
    inv[nt] = 1.0f / (l + sinkw);
  }
#pragma unroll
  for (int mt = 0; mt < 4; ++mt) {
#pragma unroll
    for (int nt = 0; nt < 2; ++nt) {
      const int t_g = q0 + w * 32 + nt * 16 + (lane & 15);
      const int d0 = mt * 16 + (lane >> 4) * 4;
      ushort4 o;
      o.x = f2bf(acc[mt][nt][0] * inv[nt]);
      o.y = f2bf(acc[mt][nt][1] * inv[nt]);
      o.z = f2bf(acc[mt][nt][2] * inv[nt]);
      o.w = f2bf(acc[mt][nt][3] * inv[nt]);
      *(ushort4*)&AO[(size_t)(b * CT + t_g) * CD + h * CHD + d0] = o;
    }
  }
}

extern "C" void kernel_launch(void* const* d_in, const int* in_sizes, int n_in,
                              void* d_out, int out_size, void* d_ws, size_t ws_size,
                              hipStream_t stream) {
  (void)in_sizes;
  (void)n_in;
  (void)out_size;
  (void)ws_size;
  const float* x = (const float*)d_in[0];
  const float* Wq = (const float*)d_in[1];
  const float* Wk = (const float*)d_in[2];
  const float* Wv = (const float*)d_in[3];
  const float* Wo = (const float*)d_in[4];
  const float* q_scale = (const float*)d_in[5];
  const float* k_scale = (const float*)d_in[6];
  const float* sink = (const float*)d_in[7];
  float* out = (float*)d_out;

  const size_t per = (size_t)CB * CH * CT * CHD;  // 4M elements
  unsigned short* Qh = (unsigned short*)d_ws;     // [B,H,T,HD]
  unsigned short* Kh = Qh + per;                  // [B,H,T,HD]
  unsigned short* Vt = Kh + per;                  // [B,H,HD,T]
  unsigned short* AO = Vt + per;                  // [B*T, D]
  unsigned short* xb = AO + per;                  // [B*T, D]
  unsigned short* WqT = xb + per;                 // [N,K] each
  unsigned short* WkT = WqT + (size_t)CD * CD;
  unsigned short* WvT = WkT + (size_t)CD * CD;
  unsigned short* WoT = WvT + (size_t)CD * CD;

  dim3 blk(256);
  cvt_all<<<dim3(16, 16, 12), blk, 0, stream>>>(x, Wq, Wk, Wv, Wo, xb, WqT, WkT, WvT, WoT);
  gemm_qkv_mfma<<<dim3(32, 8, 3), blk, 0, stream>>>(xb, WqT, WkT, WvT, Qh, Kh, Vt, q_scale, k_scale);
  attn_mfma<<<dim3(CT / 128, CB * CH), blk, 0, stream>>>(Qh, Kh, Vt, sink, AO);
  gemm_out_mfma<<<dim3(32, 8), blk, 0, stream>>>(AO, WoT, out);
}

// Round 7
// 170.780 us; speedup vs baseline: 4.4224x; 1.0145x over previous
//
#include <hip/hip_runtime.h>
#include <math.h>

#define CB 2
#define CT 2048
#define CD 1024
#define CH 16
#define CHD 64
#define CWINDOW 512

typedef __bf16 bf16x8 __attribute__((ext_vector_type(8)));
typedef float floatx4 __attribute__((ext_vector_type(4)));

__device__ __forceinline__ unsigned short f2bf(float f) {
  union { float f; unsigned int u; } v;
  v.f = f;
  unsigned int u = v.u;
  u += 0x7fffu + ((u >> 16) & 1u);  // round-to-nearest-even
  return (unsigned short)(u >> 16);
}
__device__ __forceinline__ float bf2f(unsigned int h) {
  union { unsigned int u; float f; } v;
  v.u = h << 16;
  return v.f;
}

// ---------------- fused convert: weights transpose->bf16 [N,K] + x->bf16 ----------------
// grid (16,16,12): z<4 -> weight tile (Wq,Wk,Wv,Wo); z>=4 -> x chunk.
__global__ __launch_bounds__(256) void cvt_all(const float* __restrict__ x,
                                               const float* __restrict__ Wq,
                                               const float* __restrict__ Wk,
                                               const float* __restrict__ Wv,
                                               const float* __restrict__ Wo,
                                               unsigned short* __restrict__ xb,
                                               unsigned short* __restrict__ WqT,
                                               unsigned short* __restrict__ WkT,
                                               unsigned short* __restrict__ WvT,
                                               unsigned short* __restrict__ WoT) {
  const int z = blockIdx.z;
  if (z < 4) {
    const float* W = z == 0 ? Wq : z == 1 ? Wk : z == 2 ? Wv : Wo;
    unsigned short* Wt = z == 0 ? WqT : z == 1 ? WkT : z == 2 ? WvT : WoT;
    __shared__ float tile[64][65];
    const int k0 = blockIdx.x * 64, n0 = blockIdx.y * 64;
    const int c = threadIdx.x & 63, r4 = threadIdx.x >> 6;
#pragma unroll
    for (int i = 0; i < 16; ++i) {
      int r = i * 4 + r4;
      tile[r][c] = W[(size_t)(k0 + r) * CD + n0 + c];
    }
    __syncthreads();
#pragma unroll
    for (int i = 0; i < 16; ++i) {
      int r = i * 4 + r4;
      Wt[(size_t)(n0 + r) * CD + k0 + c] = f2bf(tile[c][r]);
    }
  } else {
    const int idx = (z - 4) * 256 + blockIdx.y * 16 + blockIdx.x;
    const int i = idx * 256 + threadIdx.x;  // 8 floats per thread
    float4 a = ((const float4*)x)[i * 2];
    float4 b = ((const float4*)x)[i * 2 + 1];
    uint4 o;
    o.x = (unsigned int)f2bf(a.x) | ((unsigned int)f2bf(a.y) << 16);
    o.y = (unsigned int)f2bf(a.z) | ((unsigned int)f2bf(a.w) << 16);
    o.z = (unsigned int)f2bf(b.x) | ((unsigned int)f2bf(b.y) << 16);
    o.w = (unsigned int)f2bf(b.z) | ((unsigned int)f2bf(b.w) << 16);
    ((uint4*)xb)[i] = o;
  }
}

// ---------------- async 16B global -> LDS ----------------
__device__ __forceinline__ void async16(const unsigned short* g, unsigned short* l) {
  __builtin_amdgcn_global_load_lds(
      (const __attribute__((address_space(1))) unsigned int*)g,
      (__attribute__((address_space(3))) unsigned int*)l, 16, 0, 0);
}

// ---------------- bf16 MFMA GEMM: C[M,N] = A[M,K] @ Bt[N,K]^T ----------------
// BMx128 tile (BM=128 or 64), BK=32, 256 threads = 4 waves; wave quadrant is
// (BM/2)x64, i.e. MT x 4 tiles of 16x16x32 MFMA (MT = BM/32).
// MODE 0: C fp32 row-major [M,N].
// MODE 1: fused rmsnorm+rope epilogue, C bf16 [B,H,T,HD] (Q oscale=0.125, K 1).
// MODE 2: C bf16 scattered to [B,H,HD,T] (transposed V), packed 8B stores.
template <int MODE, int BM>
__device__ __forceinline__ void mfma_gemm_body(const unsigned short* __restrict__ A,
                                               const unsigned short* __restrict__ Bt,
                                               void* __restrict__ Cout,
                                               const float* __restrict__ scale,
                                               float oscale) {
  constexpr int K = CD;
  constexpr int MT = BM / 32;  // m-tiles per wave
  __shared__ unsigned short As[BM * 32];
  __shared__ unsigned short Bs[128 * 32];
  const int tid = threadIdx.x;
  const int wave = tid >> 6, lane = tid & 63;
  const int m0 = blockIdx.x * BM, n0 = blockIdx.y * 128;
  const int mq = (wave & 1) * (BM / 2), nq = (wave >> 1) * 64;

  floatx4 acc[MT][4] = {};
  const int srow = lane >> 2;
  const int skc = (lane & 3) * 8;
  const int fr = lane & 15;
  const int fk = (lane >> 4) * 8;

  for (int k0 = 0; k0 < K; k0 += 32) {
    __syncthreads();
#pragma unroll
    for (int it = 0; it < BM / 64; ++it) {
      const int sub = wave * (BM / 64) + it;
      const int row = sub * 16 + srow;
      async16(A + (size_t)(m0 + row) * K + k0 + skc, &As[sub * 512]);
    }
#pragma unroll
    for (int it = 0; it < 2; ++it) {
      const int sub = wave * 2 + it;
      const int row = sub * 16 + srow;
      async16(Bt + (size_t)(n0 + row) * K + k0 + skc, &Bs[sub * 512]);
    }
    __syncthreads();
    bf16x8 af[MT], bg[4];
#pragma unroll
    for (int mt = 0; mt < MT; ++mt)
      af[mt] = *(const bf16x8*)&As[(mq + mt * 16 + fr) * 32 + fk];
#pragma unroll
    for (int nt = 0; nt < 4; ++nt)
      bg[nt] = *(const bf16x8*)&Bs[(nq + nt * 16 + fr) * 32 + fk];
#pragma unroll
    for (int mt = 0; mt < MT; ++mt)
#pragma unroll
      for (int nt = 0; nt < 4; ++nt)
        acc[mt][nt] = __builtin_amdgcn_mfma_f32_16x16x32_bf16(af[mt], bg[nt], acc[mt][nt], 0, 0, 0);
  }

  // epilogue: C/D layout col=lane&15, row=(lane>>4)*4+i
  if (MODE == 1) {
    // rows = tokens; cols within quadrant = one head's 64 dims (d = nt*16+c).
    const int c = lane & 15, g = lane >> 4;
    const int hh = (n0 + nq) >> 6;  // head index (wave-uniform)
    const float kf = -0.2878231366242557f;  // -ln(10000)/32
    const float inv0 = __expf((float)c * kf);
    const float inv1 = __expf((float)(16 + c) * kf);
    float sc[4];
#pragma unroll
    for (int nt = 0; nt < 4; ++nt) sc[nt] = scale[nt * 16 + c];
#pragma unroll
    for (int mt = 0; mt < MT; ++mt) {
#pragma unroll
      for (int i = 0; i < 4; ++i) {
        const int m = m0 + mq + mt * 16 + g * 4 + i;
        const int b = m >> 11, t = m & (CT - 1);
        float v0 = acc[mt][0][i], v1 = acc[mt][1][i];
        float v2 = acc[mt][2][i], v3 = acc[mt][3][i];
        float ss = v0 * v0 + v1 * v1 + v2 * v2 + v3 * v3;
#pragma unroll
        for (int off = 8; off > 0; off >>= 1) ss += __shfl_xor(ss, off);
        const float rs = rsqrtf(ss * (1.0f / 64.0f) + 1e-6f);
        v0 *= rs * sc[0];
        v1 *= rs * sc[1];
        v2 *= rs * sc[2];
        v3 *= rs * sc[3];
        const float tf = (float)t;
        const float a0 = tf * inv0, a1 = tf * inv1;
        const float s0 = __sinf(a0), c0 = __cosf(a0);
        const float s1 = __sinf(a1), c1 = __cosf(a1);
        unsigned short* dst = (unsigned short*)Cout + ((size_t)(b * CH + hh) * CT + t) * CHD;
        dst[c] = f2bf((v0 * c0 - v2 * s0) * oscale);
        dst[16 + c] = f2bf((v1 * c1 - v3 * s1) * oscale);
        dst[32 + c] = f2bf((v2 * c0 + v0 * s0) * oscale);
        dst[48 + c] = f2bf((v3 * c1 + v1 * s1) * oscale);
      }
    }
  } else {
#pragma unroll
    for (int mt = 0; mt < MT; ++mt) {
#pragma unroll
      for (int nt = 0; nt < 4; ++nt) {
        const int col = n0 + nq + nt * 16 + (lane & 15);
        if (MODE == 2) {
          const int mb = m0 + mq + mt * 16 + (lane >> 4) * 4;
          const int b = mb >> 11, t = mb & (CT - 1);
          const int h = col >> 6, d = col & 63;
          ushort4 o;
          o.x = f2bf(acc[mt][nt][0]);
          o.y = f2bf(acc[mt][nt][1]);
          o.z = f2bf(acc[mt][nt][2]);
          o.w = f2bf(acc[mt][nt][3]);
          *(ushort4*)&((unsigned short*)Cout)[((size_t)(b * CH + h) * CHD + d) * CT + t] = o;
        } else {
#pragma unroll
          for (int i = 0; i < 4; ++i) {
            const int m = m0 + mq + mt * 16 + (lane >> 4) * 4 + i;
            ((float*)Cout)[(size_t)m * CD + col] = acc[mt][nt][i];
          }
        }
      }
    }
  }
}

// z=0: Q (norm+rope, 0.125), z=1: K (norm+rope), z=2: V transposed
__global__ __launch_bounds__(256, 3) void gemm_qkv_mfma(const unsigned short* __restrict__ xb,
                                                        const unsigned short* __restrict__ WqT,
                                                        const unsigned short* __restrict__ WkT,
                                                        const unsigned short* __restrict__ WvT,
                                                        unsigned short* __restrict__ Qh,
                                                        unsigned short* __restrict__ Kh,
                                                        unsigned short* __restrict__ Vt,
                                                        const float* __restrict__ q_scale,
                                                        const float* __restrict__ k_scale) {
  if (blockIdx.z == 2) {
    mfma_gemm_body<2, 128>(xb, WvT, Vt, nullptr, 1.0f);
  } else if (blockIdx.z == 0) {
    mfma_gemm_body<1, 128>(xb, WqT, Qh, q_scale, 0.125f);
  } else {
    mfma_gemm_body<1, 128>(xb, WkT, Kh, k_scale, 1.0f);
  }
}

// 64x128 tile -> 512 blocks (2-3/CU resident) instead of 256 (1/CU).
__global__ __launch_bounds__(256, 3) void gemm_out_mfma(const unsigned short* __restrict__ AO,
                                                        const unsigned short* __restrict__ WoT,
                                                        float* __restrict__ out) {
  mfma_gemm_body<0, 64>(AO, WoT, out, nullptr, 1.0f);
}

// ---------------- MFMA windowed attention with sink ----------------
// Grid (T/128, B*H), 256 threads = 4 waves; wave w owns queries [q0+w*32, +32).
// Per 64-key block: S^T = K·Q^T (MFMA); P = exp(S) (m=0 shift; |S|<=8 by rmsnorm);
// O^T += Vt·P. Fully-masked tiles skipped per-wave (uniform branch).
__device__ __forceinline__ bf16x8 frag64(const unsigned short* base, int row, int ks, int lane) {
  const int phys = (((ks << 2) + (lane >> 4)) ^ (lane & 7)) << 3;
  return *(const bf16x8*)&base[(row << 6) + phys];
}

__global__ __launch_bounds__(256, 2) void attn_mfma(const unsigned short* __restrict__ Qh,
                                                    const unsigned short* __restrict__ Kh,
                                                    const unsigned short* __restrict__ Vt,
                                                    const float* __restrict__ sink_logit,
                                                    unsigned short* __restrict__ AO) {
  __shared__ unsigned short Qs[128 * 64];
  __shared__ unsigned short Ks[64 * 64];
  __shared__ unsigned short Vs[64 * 64];
  __shared__ unsigned short Ps[128 * 72];  // [q][s], stride 72

  const int tid = threadIdx.x;
  const int w = tid >> 6, lane = tid & 63;
  const int qb = blockIdx.x, bh = blockIdx.y;
  const int b = bh >> 4, h = bh & 15;
  const int q0 = qb * 128;
  const unsigned short* Qb = Qh + (size_t)bh * CT * CHD;
  const unsigned short* Kb = Kh + (size_t)bh * CT * CHD;
  const unsigned short* Vb = Vt + (size_t)bh * CHD * CT;

  const int l7 = lane & 7, l8 = lane >> 3;
  const int sx8 = (l7 ^ l8) * 8;  // xor-swizzled source chunk

  // ---- stage Q tile (128 rows): 16 slabs of 8 rows, 4 per wave ----
#pragma unroll
  for (int s = 0; s < 4; ++s) {
    const int slab = w * 4 + s;
    async16(Qb + (size_t)(q0 + slab * 8 + l8) * CHD + sx8, &Qs[slab * 512]);
  }
  __syncthreads();
  bf16x8 qf[2][2];
#pragma unroll
  for (int nt = 0; nt < 2; ++nt)
#pragma unroll
    for (int ks = 0; ks < 2; ++ks)
      qf[nt][ks] = frag64(Qs, w * 32 + nt * 16 + (lane & 15), ks, lane);

  floatx4 acc[4][2] = {};  // O^T tiles: [mt over d][nt over q]
  float lsum[2] = {0.f, 0.f};
  const int qw = q0 + w * 32;  // wave's first query

  const int kb_lo = (qb >= 4) ? (qb * 2 - 8) : 0;
  const int kb_hi = qb * 2 + 1;
  for (int kb = kb_lo; kb <= kb_hi; ++kb) {
    __syncthreads();
#pragma unroll
    for (int s = 0; s < 2; ++s) {
      const int slab = w * 2 + s;
      const int row = slab * 8 + l8;
      async16(Kb + (size_t)(kb * 64 + row) * CHD + sx8, &Ks[slab * 512]);
      async16(Vb + (size_t)row * CT + kb * 64 + sx8, &Vs[slab * 512]);
    }
    __syncthreads();

    const int kmin = kb * 64, kmax = kb * 64 + 63;
    if (kmin > qw + 31 || kmax <= qw - CWINDOW) continue;  // fully masked for this wave

    // ---- S^T = K · Q^T ----
    floatx4 st[4][2] = {};
#pragma unroll
    for (int ks = 0; ks < 2; ++ks) {
      bf16x8 kf[4];
#pragma unroll
      for (int mt = 0; mt < 4; ++mt)
        kf[mt] = frag64(Ks, mt * 16 + (lane & 15), ks, lane);
#pragma unroll
      for (int mt = 0; mt < 4; ++mt)
#pragma unroll
        for (int nt = 0; nt < 2; ++nt)
          st[mt][nt] = __builtin_amdgcn_mfma_f32_16x16x32_bf16(kf[mt], qf[nt][ks], st[mt][nt], 0, 0, 0);
    }

    // ---- P = exp(S), pack to LDS [q][s], accumulate row sums ----
    const bool need_c = (kmax > qw);
    const bool need_w = (kmin <= qw + 31 - CWINDOW);
#pragma unroll
    for (int mt = 0; mt < 4; ++mt) {
#pragma unroll
      for (int nt = 0; nt < 2; ++nt) {
        const int s_base = kb * 64 + mt * 16 + (lane >> 4) * 4;
        const int t_g = q0 + w * 32 + nt * 16 + (lane & 15);
        ushort4 pk;
        float psum = 0.f;
#pragma unroll
        for (int i = 0; i < 4; ++i) {
          float sv = st[mt][nt][i];
          if (need_c || need_w) {
            const int s_g = s_base + i;
            const bool ok = (!need_c || (s_g <= t_g)) && (!need_w || (s_g > t_g - CWINDOW));
            sv = ok ? sv : -INFINITY;
          }
          const float p = __expf(sv);
          const unsigned short pb = f2bf(p);
          ((unsigned short*)&pk)[i] = pb;
          psum += bf2f(pb);
        }
        lsum[nt] += psum;
        const int qrow = w * 32 + nt * 16 + (lane & 15);
        const int scol = mt * 16 + (lane >> 4) * 4;
        *(ushort4*)&Ps[qrow * 72 + scol] = pk;
      }
    }

    // ---- O^T += Vt · P ----
#pragma unroll
    for (int ks = 0; ks < 2; ++ks) {
      bf16x8 vf[4], pf[2];
#pragma unroll
      for (int mt = 0; mt < 4; ++mt)
        vf[mt] = frag64(Vs, mt * 16 + (lane & 15), ks, lane);
#pragma unroll
      for (int nt = 0; nt < 2; ++nt) {
        const int qrow = w * 32 + nt * 16 + (lane & 15);
        pf[nt] = *(const bf16x8*)&Ps[qrow * 72 + ks * 32 + (lane >> 4) * 8];
      }
#pragma unroll
      for (int mt = 0; mt < 4; ++mt)
#pragma unroll
        for (int nt = 0; nt < 2; ++nt)
          acc[mt][nt] = __builtin_amdgcn_mfma_f32_16x16x32_bf16(vf[mt], pf[nt], acc[mt][nt], 0, 0, 0);
    }
  }

  // ---- finalize: denominator (+ sink), normalize, store O ----
  const float sinkw = __expf(sink_logit[h]);
  float inv[2];
#pragma unroll
  for (int nt = 0; nt < 2; ++nt) {
    float l = lsum[nt];
    l += __shfl_xor(l, 16);
    l += __shfl_xor(l, 32);
    inv[nt] = 1.0f / (l + sinkw);
  }
#pragma unroll
  for (int mt = 0; mt < 4; ++mt) {
#pragma unroll
    for (int nt = 0; nt < 2; ++nt) {
      const int t_g = q0 + w * 32 + nt * 16 + (lane & 15);
      const int d0 = mt * 16 + (lane >> 4) * 4;
      ushort4 o;
      o.x = f2bf(acc[mt][nt][0] * inv[nt]);
      o.y = f2bf(acc[mt][nt][1] * inv[nt]);
      o.z = f2bf(acc[mt][nt][2] * inv[nt]);
      o.w = f2bf(acc[mt][nt][3] * inv[nt]);
      *(ushort4*)&AO[(size_t)(b * CT + t_g) * CD + h * CHD + d0] = o;
    }
  }
}

extern "C" void kernel_launch(void* const* d_in, const int* in_sizes, int n_in,
                              void* d_out, int out_size, void* d_ws, size_t ws_size,
                              hipStream_t stream) {
  (void)in_sizes;
  (void)n_in;
  (void)out_size;
  (void)ws_size;
  const float* x = (const float*)d_in[0];
  const float* Wq = (const float*)d_in[1];
  const float* Wk = (const float*)d_in[2];
  const float* Wv = (const float*)d_in[3];
  const float* Wo = (const float*)d_in[4];
  const float* q_scale = (const float*)d_in[5];
  const float* k_scale = (const float*)d_in[6];
  const float* sink = (const float*)d_in[7];
  float* out = (float*)d_out;

  const size_t per = (size_t)CB * CH * CT * CHD;  // 4M elements
  unsigned short* Qh = (unsigned short*)d_ws;     // [B,H,T,HD]
  unsigned short* Kh = Qh + per;                  // [B,H,T,HD]
  unsigned short* Vt = Kh + per;                  // [B,H,HD,T]
  unsigned short* AO = Vt + per;                  // [B*T, D]
  unsigned short* xb = AO + per;                  // [B*T, D]
  unsigned short* WqT = xb + per;                 // [N,K] each
  unsigned short* WkT = WqT + (size_t)CD * CD;
  unsigned short* WvT = WkT + (size_t)CD * CD;
  unsigned short* WoT = WvT + (size_t)CD * CD;

  dim3 blk(256);
  cvt_all<<<dim3(16, 16, 12), blk, 0, stream>>>(x, Wq, Wk, Wv, Wo, xb, WqT, WkT, WvT, WoT);
  gemm_qkv_mfma<<<dim3(32, 8, 3), blk, 0, stream>>>(xb, WqT, WkT, WvT, Qh, Kh, Vt, q_scale, k_scale);
  attn_mfma<<<dim3(CT / 128, CB * CH), blk, 0, stream>>>(Qh, Kh, Vt, sink, AO);
  gemm_out_mfma<<<dim3(64, 8), blk, 0, stream>>>(AO, WoT, out);
}

// Round 8
// 169.065 us; speedup vs baseline: 4.4673x; 1.0101x over previous
//
#include <hip/hip_runtime.h>
#include <math.h>

#define CB 2
#define CT 2048
#define CD 1024
#define CH 16
#define CHD 64
#define CWINDOW 512

typedef __bf16 bf16x8 __attribute__((ext_vector_type(8)));
typedef float floatx4 __attribute__((ext_vector_type(4)));

__device__ __forceinline__ unsigned short f2bf(float f) {
  union { float f; unsigned int u; } v;
  v.f = f;
  unsigned int u = v.u;
  u += 0x7fffu + ((u >> 16) & 1u);  // round-to-nearest-even
  return (unsigned short)(u >> 16);
}
__device__ __forceinline__ float bf2f(unsigned int h) {
  union { unsigned int u; float f; } v;
  v.u = h << 16;
  return v.f;
}

// ---------------- fused convert: weights transpose->bf16 [N,K] + x->bf16 ----------------
// grid (16,16,12): z<4 -> weight tile (Wq,Wk,Wv,Wo); z>=4 -> x chunk.
__global__ __launch_bounds__(256) void cvt_all(const float* __restrict__ x,
                                               const float* __restrict__ Wq,
                                               const float* __restrict__ Wk,
                                               const float* __restrict__ Wv,
                                               const float* __restrict__ Wo,
                                               unsigned short* __restrict__ xb,
                                               unsigned short* __restrict__ WqT,
                                               unsigned short* __restrict__ WkT,
                                               unsigned short* __restrict__ WvT,
                                               unsigned short* __restrict__ WoT) {
  const int z = blockIdx.z;
  if (z < 4) {
    const float* W = z == 0 ? Wq : z == 1 ? Wk : z == 2 ? Wv : Wo;
    unsigned short* Wt = z == 0 ? WqT : z == 1 ? WkT : z == 2 ? WvT : WoT;
    __shared__ float tile[64][65];
    const int k0 = blockIdx.x * 64, n0 = blockIdx.y * 64;
    const int c = threadIdx.x & 63, r4 = threadIdx.x >> 6;
#pragma unroll
    for (int i = 0; i < 16; ++i) {
      int r = i * 4 + r4;
      tile[r][c] = W[(size_t)(k0 + r) * CD + n0 + c];
    }
    __syncthreads();
#pragma unroll
    for (int i = 0; i < 16; ++i) {
      int r = i * 4 + r4;
      Wt[(size_t)(n0 + r) * CD + k0 + c] = f2bf(tile[c][r]);
    }
  } else {
    const int idx = (z - 4) * 256 + blockIdx.y * 16 + blockIdx.x;
    const int i = idx * 256 + threadIdx.x;  // 8 floats per thread
    float4 a = ((const float4*)x)[i * 2];
    float4 b = ((const float4*)x)[i * 2 + 1];
    uint4 o;
    o.x = (unsigned int)f2bf(a.x) | ((unsigned int)f2bf(a.y) << 16);
    o.y = (unsigned int)f2bf(a.z) | ((unsigned int)f2bf(a.w) << 16);
    o.z = (unsigned int)f2bf(b.x) | ((unsigned int)f2bf(b.y) << 16);
    o.w = (unsigned int)f2bf(b.z) | ((unsigned int)f2bf(b.w) << 16);
    ((uint4*)xb)[i] = o;
  }
}

// ---------------- async 16B global -> LDS ----------------
__device__ __forceinline__ void async16(const unsigned short* g, unsigned short* l) {
  __builtin_amdgcn_global_load_lds(
      (const __attribute__((address_space(1))) unsigned int*)g,
      (__attribute__((address_space(3))) unsigned int*)l, 16, 0, 0);
}

// ---------------- bf16 MFMA GEMM: C[M,N] = A[M,K] @ Bt[N,K]^T ----------------
// BMx128 tile, BK=32, 256 threads = 4 waves; wave quadrant (BM/2)x64.
// MODE 0: C fp32 row-major [M,N].
// MODE 1: fused rmsnorm+rope epilogue, C bf16 [B,H,T,HD] in PERMUTED row layout:
//         stored pos 4c+j holds logical d = c+16j (c in [0,16), j in [0,4)).
//         Q and K share the permutation -> QK^T invariant. Packed ushort4 stores.
// MODE 2: C bf16 scattered to [B,H,HD,T] (transposed V, canonical d), 8B stores.
template <int MODE, int BM>
__device__ __forceinline__ void mfma_gemm_body(const unsigned short* __restrict__ A,
                                               const unsigned short* __restrict__ Bt,
                                               void* __restrict__ Cout,
                                               const float* __restrict__ scale,
                                               float oscale) {
  constexpr int K = CD;
  constexpr int MT = BM / 32;  // m-tiles per wave
  __shared__ unsigned short As[BM * 32];
  __shared__ unsigned short Bs[128 * 32];
  const int tid = threadIdx.x;
  const int wave = tid >> 6, lane = tid & 63;
  const int m0 = blockIdx.x * BM, n0 = blockIdx.y * 128;
  const int mq = (wave & 1) * (BM / 2), nq = (wave >> 1) * 64;

  floatx4 acc[MT][4] = {};
  const int srow = lane >> 2;
  const int skc = (lane & 3) * 8;
  const int fr = lane & 15;
  const int fk = (lane >> 4) * 8;

  for (int k0 = 0; k0 < K; k0 += 32) {
    __syncthreads();
#pragma unroll
    for (int it = 0; it < BM / 64; ++it) {
      const int sub = wave * (BM / 64) + it;
      const int row = sub * 16 + srow;
      async16(A + (size_t)(m0 + row) * K + k0 + skc, &As[sub * 512]);
    }
#pragma unroll
    for (int it = 0; it < 2; ++it) {
      const int sub = wave * 2 + it;
      const int row = sub * 16 + srow;
      async16(Bt + (size_t)(n0 + row) * K + k0 + skc, &Bs[sub * 512]);
    }
    __syncthreads();
    bf16x8 af[MT], bg[4];
#pragma unroll
    for (int mt = 0; mt < MT; ++mt)
      af[mt] = *(const bf16x8*)&As[(mq + mt * 16 + fr) * 32 + fk];
#pragma unroll
    for (int nt = 0; nt < 4; ++nt)
      bg[nt] = *(const bf16x8*)&Bs[(nq + nt * 16 + fr) * 32 + fk];
#pragma unroll
    for (int mt = 0; mt < MT; ++mt)
#pragma unroll
      for (int nt = 0; nt < 4; ++nt)
        acc[mt][nt] = __builtin_amdgcn_mfma_f32_16x16x32_bf16(af[mt], bg[nt], acc[mt][nt], 0, 0, 0);
  }

  // epilogue: C/D layout col=lane&15, row=(lane>>4)*4+i
  if (MODE == 1) {
    // rows = tokens; quadrant cols = one head's 64 dims; lane holds d={c,16+c,32+c,48+c}.
    const int c = lane & 15;
    const int g = lane >> 4;
    const int hh = (n0 + nq) >> 6;  // head index (wave-uniform)
    const float kf = -0.2878231366242557f;  // -ln(10000)/32
    const float inv0 = __expf((float)c * kf);
    const float inv1 = __expf((float)(16 + c) * kf);
    float sc[4];
#pragma unroll
    for (int nt = 0; nt < 4; ++nt) sc[nt] = scale[nt * 16 + c];
#pragma unroll
    for (int mt = 0; mt < MT; ++mt) {
#pragma unroll
      for (int i = 0; i < 4; ++i) {
        const int m = m0 + mq + mt * 16 + g * 4 + i;
        const int b = m >> 11, t = m & (CT - 1);
        float v0 = acc[mt][0][i], v1 = acc[mt][1][i];
        float v2 = acc[mt][2][i], v3 = acc[mt][3][i];
        float ss = v0 * v0 + v1 * v1 + v2 * v2 + v3 * v3;
#pragma unroll
        for (int off = 8; off > 0; off >>= 1) ss += __shfl_xor(ss, off);
        const float rs = rsqrtf(ss * (1.0f / 64.0f) + 1e-6f);
        v0 *= rs * sc[0];
        v1 *= rs * sc[1];
        v2 *= rs * sc[2];
        v3 *= rs * sc[3];
        const float tf = (float)t;
        const float a0 = tf * inv0, a1 = tf * inv1;
        const float s0 = __sinf(a0), c0 = __cosf(a0);
        const float s1 = __sinf(a1), c1 = __cosf(a1);
        unsigned short* dst = (unsigned short*)Cout + ((size_t)(b * CH + hh) * CT + t) * CHD;
        ushort4 o;
        o.x = f2bf((v0 * c0 - v2 * s0) * oscale);  // logical d = c      -> pos 4c+0
        o.y = f2bf((v1 * c1 - v3 * s1) * oscale);  // logical d = 16+c   -> pos 4c+1
        o.z = f2bf((v2 * c0 + v0 * s0) * oscale);  // logical d = 32+c   -> pos 4c+2
        o.w = f2bf((v3 * c1 + v1 * s1) * oscale);  // logical d = 48+c   -> pos 4c+3
        *(ushort4*)&dst[4 * c] = o;
      }
    }
  } else {
#pragma unroll
    for (int mt = 0; mt < MT; ++mt) {
#pragma unroll
      for (int nt = 0; nt < 4; ++nt) {
        const int col = n0 + nq + nt * 16 + (lane & 15);
        if (MODE == 2) {
          const int mb = m0 + mq + mt * 16 + (lane >> 4) * 4;
          const int b = mb >> 11, t = mb & (CT - 1);
          const int h = col >> 6, d = col & 63;
          ushort4 o;
          o.x = f2bf(acc[mt][nt][0]);
          o.y = f2bf(acc[mt][nt][1]);
          o.z = f2bf(acc[mt][nt][2]);
          o.w = f2bf(acc[mt][nt][3]);
          *(ushort4*)&((unsigned short*)Cout)[((size_t)(b * CH + h) * CHD + d) * CT + t] = o;
        } else {
#pragma unroll
          for (int i = 0; i < 4; ++i) {
            const int m = m0 + mq + mt * 16 + (lane >> 4) * 4 + i;
            ((float*)Cout)[(size_t)m * CD + col] = acc[mt][nt][i];
          }
        }
      }
    }
  }
}

// z=0: Q (norm+rope, 0.125), z=1: K (norm+rope), z=2: V transposed
__global__ __launch_bounds__(256, 3) void gemm_qkv_mfma(const unsigned short* __restrict__ xb,
                                                        const unsigned short* __restrict__ WqT,
                                                        const unsigned short* __restrict__ WkT,
                                                        const unsigned short* __restrict__ WvT,
                                                        unsigned short* __restrict__ Qh,
                                                        unsigned short* __restrict__ Kh,
                                                        unsigned short* __restrict__ Vt,
                                                        const float* __restrict__ q_scale,
                                                        const float* __restrict__ k_scale) {
  if (blockIdx.z == 2) {
    mfma_gemm_body<2, 128>(xb, WvT, Vt, nullptr, 1.0f);
  } else if (blockIdx.z == 0) {
    mfma_gemm_body<1, 128>(xb, WqT, Qh, q_scale, 0.125f);
  } else {
    mfma_gemm_body<1, 128>(xb, WkT, Kh, k_scale, 1.0f);
  }
}

// 64x128 tile -> 512 blocks (2-3/CU resident).
__global__ __launch_bounds__(256, 3) void gemm_out_mfma(const unsigned short* __restrict__ AO,
                                                        const unsigned short* __restrict__ WoT,
                                                        float* __restrict__ out) {
  mfma_gemm_body<0, 64>(AO, WoT, out, nullptr, 1.0f);
}

// ---------------- MFMA windowed attention with sink ----------------
// Grid (T/128, B*H), 256 threads = 4 waves; wave w owns queries [q0+w*32, +32).
// K/V tiles double-buffered: prefetch kb+1 issued right after the iter barrier,
// compute reads the other buffer; end-of-iter barrier drains the prefetch that
// overlapped with compute -> ONE barrier per iter, staging latency hidden.
// Q/K rows are in the permuted layout (pos 4c+j = logical d c+16j) — shared by
// Q and K so QK^T is invariant; V/AO stay canonical.
__device__ __forceinline__ bf16x8 frag64(const unsigned short* base, int row, int ks, int lane) {
  const int phys = (((ks << 2) + (lane >> 4)) ^ (lane & 7)) << 3;
  return *(const bf16x8*)&base[(row << 6) + phys];
}

__global__ __launch_bounds__(256, 2) void attn_mfma(const unsigned short* __restrict__ Qh,
                                                    const unsigned short* __restrict__ Kh,
                                                    const unsigned short* __restrict__ Vt,
                                                    const float* __restrict__ sink_logit,
                                                    unsigned short* __restrict__ AO) {
  __shared__ unsigned short Qs[128 * 64];
  __shared__ unsigned short Ks[2][64 * 64];
  __shared__ unsigned short Vs[2][64 * 64];
  __shared__ unsigned short Ps[128 * 72];  // [q][s], stride 72

  const int tid = threadIdx.x;
  const int w = tid >> 6, lane = tid & 63;
  const int qb = blockIdx.x, bh = blockIdx.y;
  const int b = bh >> 4, h = bh & 15;
  const int q0 = qb * 128;
  const unsigned short* Qb = Qh + (size_t)bh * CT * CHD;
  const unsigned short* Kb = Kh + (size_t)bh * CT * CHD;
  const unsigned short* Vb = Vt + (size_t)bh * CHD * CT;

  const int l7 = lane & 7, l8 = lane >> 3;
  const int sx8 = (l7 ^ l8) * 8;  // xor-swizzled source chunk

  auto stageKV = [&](int bsel, int kb) {
#pragma unroll
    for (int s = 0; s < 2; ++s) {
      const int slab = w * 2 + s;
      const int row = slab * 8 + l8;
      async16(Kb + (size_t)(kb * 64 + row) * CHD + sx8, &Ks[bsel][slab * 512]);
      async16(Vb + (size_t)row * CT + kb * 64 + sx8, &Vs[bsel][slab * 512]);
    }
  };

  // ---- stage Q tile (128 rows) + first K/V tile ----
#pragma unroll
  for (int s = 0; s < 4; ++s) {
    const int slab = w * 4 + s;
    async16(Qb + (size_t)(q0 + slab * 8 + l8) * CHD + sx8, &Qs[slab * 512]);
  }
  const int kb_lo = (qb >= 4) ? (qb * 2 - 8) : 0;
  const int kb_hi = qb * 2 + 1;
  stageKV(0, kb_lo);
  __syncthreads();

  bf16x8 qf[2][2];
#pragma unroll
  for (int nt = 0; nt < 2; ++nt)
#pragma unroll
    for (int ks = 0; ks < 2; ++ks)
      qf[nt][ks] = frag64(Qs, w * 32 + nt * 16 + (lane & 15), ks, lane);

  floatx4 acc[4][2] = {};  // O^T tiles: [mt over d][nt over q]
  float lsum[2] = {0.f, 0.f};
  const int qw = q0 + w * 32;  // wave's first query
  int buf = 0;

  for (int kb = kb_lo; kb <= kb_hi; ++kb) {
    // prefetch next tile into the other buffer (stays in flight during compute)
    if (kb < kb_hi) stageKV(buf ^ 1, kb + 1);

    const int kmin = kb * 64, kmax = kb * 64 + 63;
    if (!(kmin > qw + 31 || kmax <= qw - CWINDOW)) {  // not fully masked for this wave
      const unsigned short* ksrc = Ks[buf];
      const unsigned short* vsrc = Vs[buf];

      // ---- S^T = K · Q^T ----
      floatx4 st[4][2] = {};
#pragma unroll
      for (int ks = 0; ks < 2; ++ks) {
        bf16x8 kf[4];
#pragma unroll
        for (int mt = 0; mt < 4; ++mt)
          kf[mt] = frag64(ksrc, mt * 16 + (lane & 15), ks, lane);
#pragma unroll
        for (int mt = 0; mt < 4; ++mt)
#pragma unroll
          for (int nt = 0; nt < 2; ++nt)
            st[mt][nt] = __builtin_amdgcn_mfma_f32_16x16x32_bf16(kf[mt], qf[nt][ks], st[mt][nt], 0, 0, 0);
      }

      // ---- P = exp(S), pack to LDS [q][s], accumulate row sums ----
      const bool need_c = (kmax > qw);
      const bool need_w = (kmin <= qw + 31 - CWINDOW);
#pragma unroll
      for (int mt = 0; mt < 4; ++mt) {
#pragma unroll
        for (int nt = 0; nt < 2; ++nt) {
          const int s_base = kb * 64 + mt * 16 + (lane >> 4) * 4;
          const int t_g = q0 + w * 32 + nt * 16 + (lane & 15);
          ushort4 pk;
          float psum = 0.f;
#pragma unroll
          for (int i = 0; i < 4; ++i) {
            float sv = st[mt][nt][i];
            if (need_c || need_w) {
              const int s_g = s_base + i;
              const bool ok = (!need_c || (s_g <= t_g)) && (!need_w || (s_g > t_g - CWINDOW));
              sv = ok ? sv : -INFINITY;
            }
            const float p = __expf(sv);
            const unsigned short pb = f2bf(p);
            ((unsigned short*)&pk)[i] = pb;
            psum += bf2f(pb);
          }
          lsum[nt] += psum;
          const int qrow = w * 32 + nt * 16 + (lane & 15);
          const int scol = mt * 16 + (lane >> 4) * 4;
          *(ushort4*)&Ps[qrow * 72 + scol] = pk;
        }
      }

      // ---- O^T += Vt · P ----
#pragma unroll
      for (int ks = 0; ks < 2; ++ks) {
        bf16x8 vf[4], pf[2];
#pragma unroll
        for (int mt = 0; mt < 4; ++mt)
          vf[mt] = frag64(vsrc, mt * 16 + (lane & 15), ks, lane);
#pragma unroll
        for (int nt = 0; nt < 2; ++nt) {
          const int qrow = w * 32 + nt * 16 + (lane & 15);
          pf[nt] = *(const bf16x8*)&Ps[qrow * 72 + ks * 32 + (lane >> 4) * 8];
        }
#pragma unroll
        for (int mt = 0; mt < 4; ++mt)
#pragma unroll
          for (int nt = 0; nt < 2; ++nt)
            acc[mt][nt] = __builtin_amdgcn_mfma_f32_16x16x32_bf16(vf[mt], pf[nt], acc[mt][nt], 0, 0, 0);
      }
    }

    buf ^= 1;
    __syncthreads();  // drains this iter's prefetch; releases the buffer we just read
  }

  // ---- finalize: denominator (+ sink), normalize, store O ----
  const float sinkw = __expf(sink_logit[h]);
  float inv[2];
#pragma unroll
  for (int nt = 0; nt < 2; ++nt) {
    float l = lsum[nt];
    l += __shfl_xor(l, 16);
    l += __shfl_xor(l, 32);
    inv[nt] = 1.0f / (l + sinkw);
  }
#pragma unroll
  for (int mt = 0; mt < 4; ++mt) {
#pragma unroll
    for (int nt = 0; nt < 2; ++nt) {
      const int t_g = q0 + w * 32 + nt * 16 + (lane & 15);
      const int d0 = mt * 16 + (lane >> 4) * 4;
      ushort4 o;
      o.x = f2bf(acc[mt][nt][0] * inv[nt]);
      o.y = f2bf(acc[mt][nt][1] * inv[nt]);
      o.z = f2bf(acc[mt][nt][2] * inv[nt]);
      o.w = f2bf(acc[mt][nt][3] * inv[nt]);
      *(ushort4*)&AO[(size_t)(b * CT + t_g) * CD + h * CHD + d0] = o;
    }
  }
}

extern "C" void kernel_launch(void* const* d_in, const int* in_sizes, int n_in,
                              void* d_out, int out_size, void* d_ws, size_t ws_size,
                              hipStream_t stream) {
  (void)in_sizes;
  (void)n_in;
  (void)out_size;
  (void)ws_size;
  const float* x = (const float*)d_in[0];
  const float* Wq = (const float*)d_in[1];
  const float* Wk = (const float*)d_in[2];
  const float* Wv = (const float*)d_in[3];
  const float* Wo = (const float*)d_in[4];
  const float* q_scale = (const float*)d_in[5];
  const float* k_scale = (const float*)d_in[6];
  const float* sink = (const float*)d_in[7];
  float* out = (float*)d_out;

  const size_t per = (size_t)CB * CH * CT * CHD;  // 4M elements
  unsigned short* Qh = (unsigned short*)d_ws;     // [B,H,T,HD] (permuted rows)
  unsigned short* Kh = Qh + per;                  // [B,H,T,HD] (permuted rows)
  unsigned short* Vt = Kh + per;                  // [B,H,HD,T]
  unsigned short* AO = Vt + per;                  // [B*T, D]
  unsigned short* xb = AO + per;                  // [B*T, D]
  unsigned short* WqT = xb + per;                 // [N,K] each
  unsigned short* WkT = WqT + (size_t)CD * CD;
  unsigned short* WvT = WkT + (size_t)CD * CD;
  unsigned short* WoT = WvT + (size_t)CD * CD;

  dim3 blk(256);
  cvt_all<<<dim3(16, 16, 12), blk, 0, stream>>>(x, Wq, Wk, Wv, Wo, xb, WqT, WkT, WvT, WoT);
  gemm_qkv_mfma<<<dim3(32, 8, 3), blk, 0, stream>>>(xb, WqT, WkT, WvT, Qh, Kh, Vt, q_scale, k_scale);
  attn_mfma<<<dim3(CT / 128, CB * CH), blk, 0, stream>>>(Qh, Kh, Vt, sink, AO);
  gemm_out_mfma<<<dim3(64, 8), blk, 0, stream>>>(AO, WoT, out);
}